// Round 9
// baseline (239.678 us; speedup 1.0000x reference)
//
#include <hip/hip_runtime.h>
#include <math.h>

#define T_TOK 4096
#define C_DIM 256
#define EPSF  1e-5f
// hd^-0.5 * log2(e): folded into q-rows of the qkv weights -> scores in log2 domain
#define SC_QL (0.17677669529663687f * 1.4426950408889634f)

typedef short  bf16x8  __attribute__((ext_vector_type(8)));
typedef float  f32x4   __attribute__((ext_vector_type(4)));
typedef ushort ushort8 __attribute__((ext_vector_type(8)));

__device__ __forceinline__ short f2bf(float f) {
    unsigned u = __builtin_bit_cast(unsigned, f);
    unsigned r = (u + 0x7FFFu + ((u >> 16) & 1u)) >> 16;
    return (short)r;
}
__device__ __forceinline__ float bf2f(ushort u) {
    return __builtin_bit_cast(float, ((unsigned)u) << 16);
}
__device__ __forceinline__ unsigned pk_bf16(float a, float b) {
    const unsigned ua = __builtin_bit_cast(unsigned, a) + 0x8000u;
    const unsigned ub = __builtin_bit_cast(unsigned, b) + 0x8000u;
    return __builtin_amdgcn_perm(ub, ua, 0x07060302u);
}
template <int CTRL>
__device__ __forceinline__ float dppf(float x) {
    return __builtin_bit_cast(float,
        __builtin_amdgcn_mov_dpp(__builtin_bit_cast(int, x), CTRL, 0xF, 0xF, true));
}
__device__ __forceinline__ float rowsum16(float x) {
    x += dppf<0xB1>(x);
    x += dppf<0x4E>(x);
    x += dppf<0x141>(x);
    x += dppf<0x140>(x);
    return x;
}
#define MFMA16(a, b, c) __builtin_amdgcn_mfma_f32_16x16x32_bf16(a, b, c, 0, 0, 0)

// ---------------------------------------------------------------------------
// prep: [0,896) weights f32->bf16 arena with LN folding; [896,1920) BN+transpose
// x[c][t] -> tin bf16 [t][c]; [1920,2368) u/d fold vectors.
// ---------------------------------------------------------------------------
__global__ __launch_bounds__(256) void prep_kernel(
    const float* __restrict__ w_in, const float* __restrict__ w_qkv,
    const float* __restrict__ w_ap, const float* __restrict__ w_ff1,
    const float* __restrict__ w_ff2, const float* __restrict__ w_out,
    const float* __restrict__ b_qkv, const float* __restrict__ b_ff1,
    const float* __restrict__ ln1_g, const float* __restrict__ ln1_b,
    const float* __restrict__ ln2_g, const float* __restrict__ ln2_b,
    ushort* __restrict__ wbuf, float* __restrict__ u_all, float* __restrict__ d_all,
    const float* __restrict__ x, const float* __restrict__ gamma,
    const float* __restrict__ beta, const float* __restrict__ mean,
    const float* __restrict__ var, ushort* __restrict__ tin)
{
    __shared__ float tile[32][33];
    if (blockIdx.x < 896) {
        const int gid = blockIdx.x * 256 + threadIdx.x;
        const int e0 = gid * 4;
        const float* src; int off;
        float4 sc = {1.f, 1.f, 1.f, 1.f};
        if (e0 < 65536)       { src = w_in;  off = e0; }
        else if (e0 < 262144) {
            src = w_qkv; off = e0 - 65536;
            sc = *(const float4*)(ln1_g + (off & 255));
            if (off < 65536) { sc.x *= SC_QL; sc.y *= SC_QL; sc.z *= SC_QL; sc.w *= SC_QL; }
        }
        else if (e0 < 327680) { src = w_ap;  off = e0 - 262144; }
        else if (e0 < 589824) {
            src = w_ff1; off = e0 - 327680;
            sc = *(const float4*)(ln2_g + (off & 255));
        }
        else if (e0 < 851968) { src = w_ff2; off = e0 - 589824; }
        else                  { src = w_out; off = e0 - 851968; }
        const float4 v = *(const float4*)(src + off);
        ushort4 o;
        o.x = (ushort)f2bf(v.x * sc.x); o.y = (ushort)f2bf(v.y * sc.y);
        o.z = (ushort)f2bf(v.z * sc.z); o.w = (ushort)f2bf(v.w * sc.w);
        *(ushort4*)(wbuf + e0) = o;
    } else if (blockIdx.x < 1920) {
        const int bidx = blockIdx.x - 896;
        const int t0 = (bidx & 127) * 32, c0 = (bidx >> 7) * 32;
        const int tx = threadIdx.x & 31, ty = threadIdx.x >> 5;
#pragma unroll
        for (int i = 0; i < 32; i += 8) {
            const int c = c0 + ty + i;
            const float a = rsqrtf(var[c] + EPSF) * gamma[c];
            const float d = beta[c] - mean[c] * a;
            tile[ty + i][tx] = x[c * T_TOK + t0 + tx] * a + d;
        }
        __syncthreads();
#pragma unroll
        for (int i = 0; i < 32; i += 8) {
            const int t = t0 + ty + i;
            tin[t * C_DIM + c0 + tx] = (ushort)f2bf(tile[tx][ty + i]);
        }
    } else {
        const int row = (blockIdx.x - 1920) * 4 + (threadIdx.x >> 6);
        const int lane = threadIdx.x & 63;
        const float* W; const float* gv; const float* bv; float bias; float qs = 1.f;
        if (row < 768) {
            W = w_qkv + (size_t)row * 256; gv = ln1_g; bv = ln1_b; bias = b_qkv[row];
            if (row < 256) qs = SC_QL;
        } else {
            const int r2 = row - 768;
            W = w_ff1 + (size_t)r2 * 256; gv = ln2_g; bv = ln2_b; bias = b_ff1[r2];
        }
        const float4 w4 = *(const float4*)(W + lane * 4);
        const float4 g4 = *(const float4*)(gv + lane * 4);
        const float4 b4 = *(const float4*)(bv + lane * 4);
        float su = w4.x * g4.x + w4.y * g4.y + w4.z * g4.z + w4.w * g4.w;
        float sd = w4.x * b4.x + w4.y * b4.y + w4.z * b4.z + w4.w * b4.w;
#pragma unroll
        for (int off = 32; off > 0; off >>= 1) {
            su += __shfl_xor(su, off);
            sd += __shfl_xor(sd, off);
        }
        if (lane == 0) {
            u_all[row] = qs * su;
            d_all[row] = qs * (sd + bias);
        }
    }
}

// ---------------------------------------------------------------------------
// Fused pre: proj_in + (LN1 folded) QKV. grid 1024 = (4 col-quarters x 256
// token-tiles), block 256 (4 waves) -> 4 INDEPENDENT blocks/CU.
// Each block: full GEMM1 (duplicated, cheap) + in-block LN stats + its
// 192-col quarter of QKV. quarter 0 also writes tok0/lnstats.
// ---------------------------------------------------------------------------
__global__ __launch_bounds__(256) void fused_pre(
    const ushort* __restrict__ tin, const ushort* __restrict__ wb_in,
    const float* __restrict__ b_in, const ushort* __restrict__ wb_qkv,
    const float* __restrict__ u_all, const float* __restrict__ d_all,
    float* __restrict__ tok0, float* __restrict__ lnstats,
    ushort* __restrict__ qkvb)
{
    __shared__ ushort Atile[16 * 264];
    __shared__ ushort Vt[16 * 264];
    __shared__ float  red[4][16][2];
    const int quarter = blockIdx.x & 3;
    const int t0 = (blockIdx.x >> 2) * 16;
    const int tid = threadIdx.x, wv = tid >> 6, lane = tid & 63;
    const int c = lane & 15, g = lane >> 4;

    {   // stage 16x256 input tile
        const int r = tid >> 4, c0 = (tid & 15) * 16;
        *(ushort8*)&Atile[r * 264 + c0]     = *(const ushort8*)(tin + (size_t)(t0 + r) * 256 + c0);
        *(ushort8*)&Atile[r * 264 + c0 + 8] = *(const ushort8*)(tin + (size_t)(t0 + r) * 256 + c0 + 8);
    }
    __syncthreads();

    // ---- GEMM1: proj_in, FULL 256 cols (4 frags/wave), duplicated per quarter
    f32x4 a1[4] = {};
#pragma unroll
    for (int kc = 0; kc < 8; ++kc) {
        const bf16x8 af = *(const bf16x8*)&Atile[c * 264 + kc * 32 + g * 8];
#pragma unroll
        for (int nf = 0; nf < 4; ++nf) {
            const bf16x8 bfv = *(const bf16x8*)(wb_in +
                (size_t)(wv * 64 + nf * 16 + c) * 256 + kc * 32 + g * 8);
            a1[nf] = MFMA16(af, bfv, a1[nf]);
        }
    }
    float s1[4] = {}, s2[4] = {};
#pragma unroll
    for (int nf = 0; nf < 4; ++nf) {
        const int col = wv * 64 + nf * 16 + c;
        const float bb = b_in[col];
#pragma unroll
        for (int rr = 0; rr < 4; ++rr) {
            const float v = a1[nf][rr] + bb;
            s1[rr] += v; s2[rr] += v * v;
            Vt[(4 * g + rr) * 264 + col] = (ushort)f2bf(v);
            if (quarter == 0) tok0[(size_t)(t0 + 4 * g + rr) * 256 + col] = v;
        }
    }
#pragma unroll
    for (int rr = 0; rr < 4; ++rr) { s1[rr] = rowsum16(s1[rr]); s2[rr] = rowsum16(s2[rr]); }
    if (c == 0) {
#pragma unroll
        for (int rr = 0; rr < 4; ++rr) {
            red[wv][4 * g + rr][0] = s1[rr];
            red[wv][4 * g + rr][1] = s2[rr];
        }
    }
    __syncthreads();

    if (tid < 32) {   // cross-wave LN reduce, overlaps GEMM2 of other waves
        const int row = tid >> 1, j = tid & 1;
        red[0][row][j] = red[0][row][j] + red[1][row][j] + red[2][row][j] + red[3][row][j];
    }

    // ---- GEMM2: QKV quarter (192 cols, 3 frags/wave), LN-folded weights ----
    f32x4 a2[3] = {};
#pragma unroll
    for (int kc = 0; kc < 8; ++kc) {
        const bf16x8 af = *(const bf16x8*)&Vt[c * 264 + kc * 32 + g * 8];
#pragma unroll
        for (int nf = 0; nf < 3; ++nf) {
            const bf16x8 bfv = *(const bf16x8*)(wb_qkv +
                (size_t)(quarter * 192 + wv * 48 + nf * 16 + c) * 256 + kc * 32 + g * 8);
            a2[nf] = MFMA16(af, bfv, a2[nf]);
        }
    }
    __syncthreads();

    float mu[4], rs[4];
#pragma unroll
    for (int rr = 0; rr < 4; ++rr) {
        const int row = 4 * g + rr;
        mu[rr] = red[0][row][0] * (1.0f / 256.0f);
        const float var = red[0][row][1] * (1.0f / 256.0f) - mu[rr] * mu[rr];
        rs[rr] = rsqrtf(var + EPSF);
    }
    if (quarter == 0 && wv == 0 && c == 0) {
#pragma unroll
        for (int rr = 0; rr < 4; ++rr) {
            lnstats[(size_t)(t0 + 4 * g + rr) * 2 + 0] = mu[rr];
            lnstats[(size_t)(t0 + 4 * g + rr) * 2 + 1] = rs[rr];
        }
    }
#pragma unroll
    for (int nf = 0; nf < 3; ++nf) {
        const int col = quarter * 192 + wv * 48 + nf * 16 + c;
        const float u = u_all[col], d = d_all[col];
#pragma unroll
        for (int rr = 0; rr < 4; ++rr) {
            const float q = rs[rr] * (a2[nf][rr] - mu[rr] * u) + d;
            qkvb[(size_t)(t0 + 4 * g + rr) * 768 + col] = (ushort)f2bf(q);
        }
    }
}

// ---------------------------------------------------------------------------
// Flash attention (unchanged from R8): no-max exp2 softmax, split-K x4.
// grid=(T/64, HEADS, 4), block=256.
// ---------------------------------------------------------------------------
#define KS   40
#define VTS  72
#define PS_W 34

__global__ __launch_bounds__(256) void attn_mfma(
    const ushort* __restrict__ qkv, ushort* __restrict__ opart,
    float* __restrict__ lpart)
{
    const int h    = blockIdx.y;
    const int q0   = blockIdx.x << 6;
    const int half = blockIdx.z;
    const int tid  = threadIdx.x;
    const int wv   = tid >> 6, lane = tid & 63;
    const int c    = lane & 15, g = lane >> 4;

    __shared__ ushort Ks[2][64 * KS];
    __shared__ ushort Vt[2][32 * VTS];
    __shared__ float  Ps[4][16 * PS_W];

    const bf16x8 qf = *(const bf16x8*)(qkv + (size_t)(q0 + wv * 16 + c) * 768 + h * 32 + g * 8);

    bf16x8 ones;
#pragma unroll
    for (int i = 0; i < 8; ++i) ones[i] = (short)0x3F80;

    f32x4 oacc0 = {0.f, 0.f, 0.f, 0.f};
    f32x4 oacc1 = {0.f, 0.f, 0.f, 0.f};
    f32x4 oaccl = {0.f, 0.f, 0.f, 0.f};

    const int kr = tid >> 2, kc = (tid & 3) * 8;
    const int vp = tid & 31, vd = (tid >> 5) * 4;
    const ushort* kbase = qkv + 256 + h * 32;
    const ushort* vbase = qkv + 512 + h * 32;

    const int kt0 = half * 16, kt1 = kt0 + 16;
    ushort8 kpre  = *(const ushort8*)(kbase + ((size_t)kt0 * 64 + kr) * 768 + kc);
    ushort4 vpre0 = *(const ushort4*)(vbase + ((size_t)kt0 * 64 + 2 * vp) * 768 + vd);
    ushort4 vpre1 = *(const ushort4*)(vbase + ((size_t)kt0 * 64 + 2 * vp + 1) * 768 + vd);

    int p = 0;
    for (int kt = kt0; kt < kt1; ++kt) {
        *(ushort8*)&Ks[p][kr * KS + kc] = kpre;
        {
            unsigned* vtp = (unsigned*)&Vt[p][0];
            vtp[(vd + 0) * (VTS / 2) + vp] = (unsigned)vpre0.x | ((unsigned)vpre1.x << 16);
            vtp[(vd + 1) * (VTS / 2) + vp] = (unsigned)vpre0.y | ((unsigned)vpre1.y << 16);
            vtp[(vd + 2) * (VTS / 2) + vp] = (unsigned)vpre0.z | ((unsigned)vpre1.z << 16);
            vtp[(vd + 3) * (VTS / 2) + vp] = (unsigned)vpre0.w | ((unsigned)vpre1.w << 16);
        }
        __syncthreads();
        if (kt + 1 < kt1) {
            const size_t t0 = (size_t)(kt + 1) * 64;
            kpre  = *(const ushort8*)(kbase + (t0 + kr) * 768 + kc);
            vpre0 = *(const ushort4*)(vbase + (t0 + 2 * vp) * 768 + vd);
            vpre1 = *(const ushort4*)(vbase + (t0 + 2 * vp + 1) * 768 + vd);
        }

        const ushort* ks = &Ks[p][0];
        const ushort* vt = &Vt[p][0];
        const f32x4 zz = {0.f, 0.f, 0.f, 0.f};
        const bf16x8 k0 = *(const bf16x8*)&ks[(0 * 16 + c) * KS + g * 8];
        const bf16x8 k1 = *(const bf16x8*)&ks[(1 * 16 + c) * KS + g * 8];
        const bf16x8 k2 = *(const bf16x8*)&ks[(2 * 16 + c) * KS + g * 8];
        const bf16x8 k3 = *(const bf16x8*)&ks[(3 * 16 + c) * KS + g * 8];
        const f32x4 s0 = MFMA16(k0, qf, zz);
        const f32x4 s1 = MFMA16(k1, qf, zz);
        const f32x4 s2 = MFMA16(k2, qf, zz);
        const f32x4 s3 = MFMA16(k3, qf, zz);

        float* prow = &Ps[wv][c * PS_W];
        {
            const float e00 = __builtin_amdgcn_exp2f(s0[0]), e01 = __builtin_amdgcn_exp2f(s0[1]);
            const float e02 = __builtin_amdgcn_exp2f(s0[2]), e03 = __builtin_amdgcn_exp2f(s0[3]);
            const float e10 = __builtin_amdgcn_exp2f(s1[0]), e11 = __builtin_amdgcn_exp2f(s1[1]);
            const float e12 = __builtin_amdgcn_exp2f(s1[2]), e13 = __builtin_amdgcn_exp2f(s1[3]);
            const float e20 = __builtin_amdgcn_exp2f(s2[0]), e21 = __builtin_amdgcn_exp2f(s2[1]);
            const float e22 = __builtin_amdgcn_exp2f(s2[2]), e23 = __builtin_amdgcn_exp2f(s2[3]);
            const float e30 = __builtin_amdgcn_exp2f(s3[0]), e31 = __builtin_amdgcn_exp2f(s3[1]);
            const float e32 = __builtin_amdgcn_exp2f(s3[2]), e33 = __builtin_amdgcn_exp2f(s3[3]);
            prow[0 * 8 + 2 * g + 0] = __builtin_bit_cast(float, pk_bf16(e00, e01));
            prow[0 * 8 + 2 * g + 1] = __builtin_bit_cast(float, pk_bf16(e02, e03));
            prow[1 * 8 + 2 * g + 0] = __builtin_bit_cast(float, pk_bf16(e10, e11));
            prow[1 * 8 + 2 * g + 1] = __builtin_bit_cast(float, pk_bf16(e12, e13));
            prow[2 * 8 + 2 * g + 0] = __builtin_bit_cast(float, pk_bf16(e20, e21));
            prow[2 * 8 + 2 * g + 1] = __builtin_bit_cast(float, pk_bf16(e22, e23));
            prow[3 * 8 + 2 * g + 0] = __builtin_bit_cast(float, pk_bf16(e30, e31));
            prow[3 * 8 + 2 * g + 1] = __builtin_bit_cast(float, pk_bf16(e32, e33));
        }
#pragma unroll
        for (int ch = 0; ch < 2; ++ch) {
            const float2 pA = *(const float2*)&prow[ch * 16 + 4 * g];
            const float2 pB = *(const float2*)&prow[ch * 16 + 4 * g + 2];
            unsigned pw[4];
            pw[0] = __builtin_bit_cast(unsigned, pA.x);
            pw[1] = __builtin_bit_cast(unsigned, pA.y);
            pw[2] = __builtin_bit_cast(unsigned, pB.x);
            pw[3] = __builtin_bit_cast(unsigned, pB.y);
            const bf16x8 pf = *(const bf16x8*)pw;
            const bf16x8 v0 = *(const bf16x8*)&vt[(c)      * VTS + ch * 32 + g * 8];
            const bf16x8 v1 = *(const bf16x8*)&vt[(16 + c) * VTS + ch * 32 + g * 8];
            oacc0 = MFMA16(pf, v0, oacc0);
            oacc1 = MFMA16(pf, v1, oacc1);
            oaccl = MFMA16(pf, ones, oaccl);
        }
        p ^= 1;
        __syncthreads();
    }

    {
        ushort* op = opart + (size_t)half * (1u << 20) + (size_t)(q0 + wv * 16) * 256 + h * 32;
#pragma unroll
        for (int rr = 0; rr < 4; ++rr) {
            op[(4 * g + rr) * 256 + c]      = (ushort)f2bf(oacc0[rr]);
            op[(4 * g + rr) * 256 + 16 + c] = (ushort)f2bf(oacc1[rr]);
        }
        if (c == 0) {
#pragma unroll
            for (int rr = 0; rr < 4; ++rr)
                lpart[(size_t)(q0 + wv * 16 + 4 * g + rr) * 32 + half * 8 + h] = oaccl[rr];
        }
    }
}

// ---------------------------------------------------------------------------
// Fused mid: combine O + attn-proj + residuals + (LN2 folded) FF1 quarter +
// gelu. grid 1024 = (4 quarters x 256 tiles), block 256.
// ---------------------------------------------------------------------------
__global__ __launch_bounds__(256) void fused_mid(
    const ushort* __restrict__ opart, const float* __restrict__ lpart,
    const ushort* __restrict__ wb_ap, const float* __restrict__ b_ap,
    const float* __restrict__ tok0, const float* __restrict__ lnstats,
    const float* __restrict__ ln1_g, const float* __restrict__ ln1_b,
    const ushort* __restrict__ wb_ff1, const float* __restrict__ u_all,
    const float* __restrict__ d_all, float* __restrict__ tok1,
    ushort* __restrict__ zbuf)
{
    __shared__ ushort Otile[16 * 264];
    __shared__ ushort Vt[16 * 264];
    __shared__ float  red[4][16][2];
    const int quarter = blockIdx.x & 3;
    const int t0 = (blockIdx.x >> 2) * 16;
    const int tid = threadIdx.x, wv = tid >> 6, lane = tid & 63;
    const int c = lane & 15, g = lane >> 4;

    {   // combine 4 O partials: 16 cols per thread
        const int r = tid >> 4, c0 = (tid & 15) * 16;
        const int h = c0 >> 5;
        const float* lp = lpart + (size_t)(t0 + r) * 32;
        const float inv = 1.0f / (lp[h] + lp[8 + h] + lp[16 + h] + lp[24 + h]);
        const size_t base = (size_t)(t0 + r) * 256 + c0;
#pragma unroll
        for (int cc = 0; cc < 16; cc += 4) {
            const ushort4 a0 = *(const ushort4*)(opart + base + cc);
            const ushort4 a1 = *(const ushort4*)(opart + (1u << 20) + base + cc);
            const ushort4 a2 = *(const ushort4*)(opart + (2u << 20) + base + cc);
            const ushort4 a3 = *(const ushort4*)(opart + (3u << 20) + base + cc);
            unsigned w[2];
            w[0] = pk_bf16((bf2f(a0.x) + bf2f(a1.x) + bf2f(a2.x) + bf2f(a3.x)) * inv,
                           (bf2f(a0.y) + bf2f(a1.y) + bf2f(a2.y) + bf2f(a3.y)) * inv);
            w[1] = pk_bf16((bf2f(a0.z) + bf2f(a1.z) + bf2f(a2.z) + bf2f(a3.z)) * inv,
                           (bf2f(a0.w) + bf2f(a1.w) + bf2f(a2.w) + bf2f(a3.w)) * inv);
            *(ushort4*)&Otile[r * 264 + c0 + cc] = *(ushort4*)w;
        }
    }
    __syncthreads();

    // ---- GEMM1: attn-proj FULL 256 cols (4 frags/wave), duplicated ----
    f32x4 a1[4] = {};
#pragma unroll
    for (int kc = 0; kc < 8; ++kc) {
        const bf16x8 af = *(const bf16x8*)&Otile[c * 264 + kc * 32 + g * 8];
#pragma unroll
        for (int nf = 0; nf < 4; ++nf) {
            const bf16x8 bfv = *(const bf16x8*)(wb_ap +
                (size_t)(wv * 64 + nf * 16 + c) * 256 + kc * 32 + g * 8);
            a1[nf] = MFMA16(af, bfv, a1[nf]);
        }
    }
    float mu1[4], rs1[4];
#pragma unroll
    for (int rr = 0; rr < 4; ++rr) {
        const int row = t0 + 4 * g + rr;
        mu1[rr] = lnstats[(size_t)row * 2 + 0];
        rs1[rr] = lnstats[(size_t)row * 2 + 1];
    }
    float s1[4] = {}, s2[4] = {};
#pragma unroll
    for (int nf = 0; nf < 4; ++nf) {
        const int col = wv * 64 + nf * 16 + c;
        const float bb = b_ap[col];
        const float g1 = ln1_g[col], b1 = ln1_b[col];
#pragma unroll
        for (int rr = 0; rr < 4; ++rr) {
            const size_t idx = (size_t)(t0 + 4 * g + rr) * 256 + col;
            const float t0v = tok0[idx];
            const float y = (t0v - mu1[rr]) * rs1[rr] * g1 + b1;
            const float v = a1[nf][rr] + bb + y + t0v;
            s1[rr] += v; s2[rr] += v * v;
            Vt[(4 * g + rr) * 264 + col] = (ushort)f2bf(v);
            if (quarter == 0) tok1[idx] = v;
        }
    }
#pragma unroll
    for (int rr = 0; rr < 4; ++rr) { s1[rr] = rowsum16(s1[rr]); s2[rr] = rowsum16(s2[rr]); }
    if (c == 0) {
#pragma unroll
        for (int rr = 0; rr < 4; ++rr) {
            red[wv][4 * g + rr][0] = s1[rr];
            red[wv][4 * g + rr][1] = s2[rr];
        }
    }
    __syncthreads();

    if (tid < 32) {
        const int row = tid >> 1, j = tid & 1;
        red[0][row][j] = red[0][row][j] + red[1][row][j] + red[2][row][j] + red[3][row][j];
    }

    // ---- GEMM2: FF1 quarter (256 of 1024 cols, 4 frags/wave) ----
    f32x4 a2[4] = {};
#pragma unroll
    for (int kc = 0; kc < 8; ++kc) {
        const bf16x8 af = *(const bf16x8*)&Vt[c * 264 + kc * 32 + g * 8];
#pragma unroll
        for (int nf = 0; nf < 4; ++nf) {
            const bf16x8 bfv = *(const bf16x8*)(wb_ff1 +
                (size_t)(quarter * 256 + wv * 64 + nf * 16 + c) * 256 + kc * 32 + g * 8);
            a2[nf] = MFMA16(af, bfv, a2[nf]);
        }
    }
    __syncthreads();

    float mu[4], rs[4];
#pragma unroll
    for (int rr = 0; rr < 4; ++rr) {
        const int row = 4 * g + rr;
        mu[rr] = red[0][row][0] * (1.0f / 256.0f);
        const float var = red[0][row][1] * (1.0f / 256.0f) - mu[rr] * mu[rr];
        rs[rr] = rsqrtf(var + EPSF);
    }
#pragma unroll
    for (int nf = 0; nf < 4; ++nf) {
        const int col = quarter * 256 + wv * 64 + nf * 16 + c;
        const float u = u_all[768 + col], d = d_all[768 + col];
#pragma unroll
        for (int rr = 0; rr < 4; ++rr) {
            float v = rs[rr] * (a2[nf][rr] - mu[rr] * u) + d;
            v = 0.5f * v * (1.0f + erff(v * 0.70710678118654752f));
            zbuf[(size_t)(t0 + 4 * g + rr) * 1024 + col] = (ushort)f2bf(v);
        }
    }
}

// ---------------------------------------------------------------------------
// FF2 quarter + residual -> tok2 bf16. grid 1024 = (4 quarters x 256 tiles).
// ---------------------------------------------------------------------------
__global__ __launch_bounds__(256) void k_ff2(
    const ushort* __restrict__ zbuf, const ushort* __restrict__ wb_ff2,
    const float* __restrict__ b_ff2, const float* __restrict__ tok1,
    ushort* __restrict__ tok2)
{
    __shared__ ushort Ztile[16 * 1032];
    const int quarter = blockIdx.x & 3;
    const int t0 = (blockIdx.x >> 2) * 16;
    const int tid = threadIdx.x, wv = tid >> 6, lane = tid & 63;
    const int c = lane & 15, g = lane >> 4;

    const int col = quarter * 64 + wv * 16 + c;
    // prefetch first 8 weight frags (barrier-independent)
    bf16x8 w2[8];
#pragma unroll
    for (int kc = 0; kc < 8; ++kc)
        w2[kc] = *(const bf16x8*)(wb_ff2 + (size_t)col * 1024 + kc * 32 + g * 8);

    {   // stage full 16x1024 zbuf tile: 64 cols/thread
        const int r = tid >> 4, c0 = (tid & 15) * 64;
#pragma unroll
        for (int i = 0; i < 8; ++i)
            *(ushort8*)&Ztile[r * 1032 + c0 + i * 8] =
                *(const ushort8*)(zbuf + (size_t)(t0 + r) * 1024 + c0 + i * 8);
    }
    __syncthreads();

    f32x4 acc = {};
#pragma unroll
    for (int kc = 0; kc < 8; ++kc) {
        const bf16x8 af = *(const bf16x8*)&Ztile[c * 1032 + kc * 32 + g * 8];
        acc = MFMA16(af, w2[kc], acc);
    }
#pragma unroll
    for (int kc = 8; kc < 32; ++kc) {
        const bf16x8 af = *(const bf16x8*)&Ztile[c * 1032 + kc * 32 + g * 8];
        const bf16x8 bfv = *(const bf16x8*)(wb_ff2 + (size_t)col * 1024 + kc * 32 + g * 8);
        acc = MFMA16(af, bfv, acc);
    }
    const float bb = b_ff2[col];
#pragma unroll
    for (int rr = 0; rr < 4; ++rr) {
        const size_t idx = (size_t)(t0 + 4 * g + rr) * 256 + col;
        tok2[idx] = (ushort)f2bf(acc[rr] + bb + tok1[idx]);
    }
}

// ---------------------------------------------------------------------------
// proj_out quarter + outer residual. grid 1024 = (4 quarters x 256 tiles).
// ---------------------------------------------------------------------------
__global__ __launch_bounds__(256) void k_pout(
    const ushort* __restrict__ tok2, const ushort* __restrict__ wb_out,
    const float* __restrict__ b_out, const float* __restrict__ x,
    float* __restrict__ out)
{
    __shared__ ushort Ttile[16 * 264];
    const int quarter = blockIdx.x & 3;
    const int t0 = (blockIdx.x >> 2) * 16;
    const int tid = threadIdx.x, wv = tid >> 6, lane = tid & 63;
    const int c = lane & 15, g = lane >> 4;

    // prefetch weight frags for this wave's 16 out-rows
    bf16x8 wo[8];
#pragma unroll
    for (int kc = 0; kc < 8; ++kc)
        wo[kc] = *(const bf16x8*)(wb_out +
            (size_t)(quarter * 64 + wv * 16 + c) * 256 + kc * 32 + g * 8);

    {   // stage tok2 16x256
        const int r = tid >> 4, c0 = (tid & 15) * 16;
        *(ushort8*)&Ttile[r * 264 + c0]     = *(const ushort8*)(tok2 + (size_t)(t0 + r) * 256 + c0);
        *(ushort8*)&Ttile[r * 264 + c0 + 8] = *(const ushort8*)(tok2 + (size_t)(t0 + r) * 256 + c0 + 8);
    }
    __syncthreads();

    f32x4 acc = {};
#pragma unroll
    for (int kc = 0; kc < 8; ++kc) {
        const bf16x8 bfr = *(const bf16x8*)&Ttile[c * 264 + kc * 32 + g * 8];
        acc = MFMA16(wo[kc], bfr, acc);
    }
#pragma unroll
    for (int rr = 0; rr < 4; ++rr) {
        const int och = quarter * 64 + wv * 16 + 4 * g + rr;
        const size_t idx = (size_t)och * T_TOK + t0 + c;
        out[idx] = acc[rr] + b_out[och] + x[idx];
    }
}

// ---------------------------------------------------------------------------
extern "C" void kernel_launch(void* const* d_in, const int* in_sizes, int n_in,
                              void* d_out, int out_size, void* d_ws, size_t ws_size,
                              hipStream_t stream)
{
    const float* x     = (const float*)d_in[0];
    const float* bn_g  = (const float*)d_in[1];
    const float* bn_b  = (const float*)d_in[2];
    const float* bn_m  = (const float*)d_in[3];
    const float* bn_v  = (const float*)d_in[4];
    const float* w_in  = (const float*)d_in[5];
    const float* b_in  = (const float*)d_in[6];
    const float* ln1_g = (const float*)d_in[7];
    const float* ln1_b = (const float*)d_in[8];
    const float* w_qkv = (const float*)d_in[9];
    const float* b_qkv = (const float*)d_in[10];
    const float* w_ap  = (const float*)d_in[11];
    const float* b_ap  = (const float*)d_in[12];
    const float* ln2_g = (const float*)d_in[13];
    const float* ln2_b = (const float*)d_in[14];
    const float* w_ff1 = (const float*)d_in[15];
    const float* b_ff1 = (const float*)d_in[16];
    const float* w_ff2 = (const float*)d_in[17];
    const float* b_ff2 = (const float*)d_in[18];
    const float* w_out = (const float*)d_in[19];
    const float* b_out = (const float*)d_in[20];
    float* out = (float*)d_out;
    float* ws  = (float*)d_ws;

    const size_t MF = 1u << 20;   // 1M f32 = 4 MB
    float*  tok0   = ws;                                   // [0,1M)
    float*  tok1   = ws + MF;                              // [1M,2M)
    float*  lnst   = ws + 2 * MF;                          // [2M, +8K f32)
    ushort* tok2   = (ushort*)(ws + 2 * MF + MF / 4);      // [2.25M,2.5M) 2 MB
    ushort* qkv_bf = (ushort*)(ws + 3 * MF);               // [3M,4.5M) 6 MB
    ushort* tin_bf = (ushort*)(ws + 4 * MF + MF / 2);      // [4.5M,5M) 2 MB
    ushort* opart  = tin_bf;                               // reuse: 4x2MB = [4.5M,6.5M)
    ushort* zbuf   = (ushort*)(ws + 6 * MF + MF / 2);      // [6.5M,8.5M) 8 MB
    float*  lpart  = ws + 8 * MF + MF / 2;                 // [8.5M, +128K f32)
    ushort* wbuf   = (ushort*)(ws + 8 * MF + MF / 2 + 131072);
    const ushort* wb_in  = wbuf;
    const ushort* wb_qkv = wbuf + 65536;
    const ushort* wb_ap  = wbuf + 262144;
    const ushort* wb_ff1 = wbuf + 327680;
    const ushort* wb_ff2 = wbuf + 589824;
    const ushort* wb_out = wbuf + 851968;
    float* u_all = (float*)(wbuf + 917504);
    float* d_all = u_all + 1792;

    prep_kernel<<<2368, 256, 0, stream>>>(
        w_in, w_qkv, w_ap, w_ff1, w_ff2, w_out,
        b_qkv, b_ff1, ln1_g, ln1_b, ln2_g, ln2_b,
        wbuf, u_all, d_all,
        x, bn_g, bn_b, bn_m, bn_v, tin_bf);
    fused_pre<<<1024, 256, 0, stream>>>(tin_bf, wb_in, b_in, wb_qkv,
                                        u_all, d_all, tok0, lnst, qkv_bf);
    attn_mfma<<<dim3(64, 8, 4), 256, 0, stream>>>(qkv_bf, opart, lpart);
    fused_mid<<<1024, 256, 0, stream>>>(opart, lpart, wb_ap, b_ap, tok0, lnst,
                                        ln1_g, ln1_b, wb_ff1, u_all, d_all,
                                        tok1, zbuf);
    k_ff2<<<1024, 256, 0, stream>>>(zbuf, wb_ff2, b_ff2, tok1, tok2);
    k_pout<<<1024, 256, 0, stream>>>(tok2, wb_out, b_out, x, out);
}

// Round 10
// 215.094 us; speedup vs baseline: 1.1143x; 1.1143x over previous
//
#include <hip/hip_runtime.h>
#include <math.h>

#define T_TOK 4096
#define C_DIM 256
#define EPSF  1e-5f
// hd^-0.5 * log2(e): folded into q-rows of the qkv weights -> scores in log2 domain
#define SC_QL (0.17677669529663687f * 1.4426950408889634f)

typedef short  bf16x8  __attribute__((ext_vector_type(8)));
typedef float  f32x4   __attribute__((ext_vector_type(4)));
typedef ushort ushort8 __attribute__((ext_vector_type(8)));

__device__ __forceinline__ short f2bf(float f) {
    unsigned u = __builtin_bit_cast(unsigned, f);
    unsigned r = (u + 0x7FFFu + ((u >> 16) & 1u)) >> 16;
    return (short)r;
}
__device__ __forceinline__ float bf2f(ushort u) {
    return __builtin_bit_cast(float, ((unsigned)u) << 16);
}
__device__ __forceinline__ unsigned pk_bf16(float a, float b) {
    const unsigned ua = __builtin_bit_cast(unsigned, a) + 0x8000u;
    const unsigned ub = __builtin_bit_cast(unsigned, b) + 0x8000u;
    return __builtin_amdgcn_perm(ub, ua, 0x07060302u);
}
#define MFMA16(a, b, c) __builtin_amdgcn_mfma_f32_16x16x32_bf16(a, b, c, 0, 0, 0)

// ---------------------------------------------------------------------------
// prep (R8, proven): weights -> bf16 arena with LN-gamma folding; BN+transpose;
// u/d fold vectors.
// ---------------------------------------------------------------------------
__global__ __launch_bounds__(256) void prep_kernel(
    const float* __restrict__ w_in, const float* __restrict__ w_qkv,
    const float* __restrict__ w_ap, const float* __restrict__ w_ff1,
    const float* __restrict__ w_ff2, const float* __restrict__ w_out,
    const float* __restrict__ b_qkv, const float* __restrict__ b_ff1,
    const float* __restrict__ ln1_g, const float* __restrict__ ln1_b,
    const float* __restrict__ ln2_g, const float* __restrict__ ln2_b,
    ushort* __restrict__ wbuf, float* __restrict__ u_all, float* __restrict__ d_all,
    const float* __restrict__ x, const float* __restrict__ gamma,
    const float* __restrict__ beta, const float* __restrict__ mean,
    const float* __restrict__ var, ushort* __restrict__ tin)
{
    __shared__ float tile[32][33];
    if (blockIdx.x < 896) {
        const int gid = blockIdx.x * 256 + threadIdx.x;
        const int e0 = gid * 4;
        const float* src; int off;
        float4 sc = {1.f, 1.f, 1.f, 1.f};
        if (e0 < 65536)       { src = w_in;  off = e0; }
        else if (e0 < 262144) {
            src = w_qkv; off = e0 - 65536;
            sc = *(const float4*)(ln1_g + (off & 255));
            if (off < 65536) { sc.x *= SC_QL; sc.y *= SC_QL; sc.z *= SC_QL; sc.w *= SC_QL; }
        }
        else if (e0 < 327680) { src = w_ap;  off = e0 - 262144; }
        else if (e0 < 589824) {
            src = w_ff1; off = e0 - 327680;
            sc = *(const float4*)(ln2_g + (off & 255));
        }
        else if (e0 < 851968) { src = w_ff2; off = e0 - 589824; }
        else                  { src = w_out; off = e0 - 851968; }
        const float4 v = *(const float4*)(src + off);
        ushort4 o;
        o.x = (ushort)f2bf(v.x * sc.x); o.y = (ushort)f2bf(v.y * sc.y);
        o.z = (ushort)f2bf(v.z * sc.z); o.w = (ushort)f2bf(v.w * sc.w);
        *(ushort4*)(wbuf + e0) = o;
    } else if (blockIdx.x < 1920) {
        const int bidx = blockIdx.x - 896;
        const int t0 = (bidx & 127) * 32, c0 = (bidx >> 7) * 32;
        const int tx = threadIdx.x & 31, ty = threadIdx.x >> 5;
#pragma unroll
        for (int i = 0; i < 32; i += 8) {
            const int c = c0 + ty + i;
            const float a = rsqrtf(var[c] + EPSF) * gamma[c];
            const float d = beta[c] - mean[c] * a;
            tile[ty + i][tx] = x[c * T_TOK + t0 + tx] * a + d;
        }
        __syncthreads();
#pragma unroll
        for (int i = 0; i < 32; i += 8) {
            const int t = t0 + ty + i;
            tin[t * C_DIM + c0 + tx] = (ushort)f2bf(tile[tx][ty + i]);
        }
    } else {
        const int row = (blockIdx.x - 1920) * 4 + (threadIdx.x >> 6);
        const int lane = threadIdx.x & 63;
        const float* W; const float* gv; const float* bv; float bias; float qs = 1.f;
        if (row < 768) {
            W = w_qkv + (size_t)row * 256; gv = ln1_g; bv = ln1_b; bias = b_qkv[row];
            if (row < 256) qs = SC_QL;
        } else {
            const int r2 = row - 768;
            W = w_ff1 + (size_t)r2 * 256; gv = ln2_g; bv = ln2_b; bias = b_ff1[r2];
        }
        const float4 w4 = *(const float4*)(W + lane * 4);
        const float4 g4 = *(const float4*)(gv + lane * 4);
        const float4 b4 = *(const float4*)(bv + lane * 4);
        float su = w4.x * g4.x + w4.y * g4.y + w4.z * g4.z + w4.w * g4.w;
        float sd = w4.x * b4.x + w4.y * b4.y + w4.z * b4.z + w4.w * b4.w;
#pragma unroll
        for (int off = 32; off > 0; off >>= 1) {
            su += __shfl_xor(su, off);
            sd += __shfl_xor(sd, off);
        }
        if (lane == 0) {
            u_all[row] = qs * su;
            d_all[row] = qs * (sd + bias);
        }
    }
}

// ---------------------------------------------------------------------------
// LN stats: one wave per row of 256 f32 -> (mu, rs). grid 1024, block 256.
// ---------------------------------------------------------------------------
__global__ __launch_bounds__(256) void k_lnstats(
    const float* __restrict__ in, float* __restrict__ st)
{
    const int row = blockIdx.x * 4 + (threadIdx.x >> 6);
    const int lane = threadIdx.x & 63;
    const float4 v = *(const float4*)(in + (size_t)row * 256 + lane * 4);
    float s  = v.x + v.y + v.z + v.w;
    float s2 = v.x * v.x + v.y * v.y + v.z * v.z + v.w * v.w;
#pragma unroll
    for (int off = 32; off > 0; off >>= 1) {
        s  += __shfl_xor(s, off);
        s2 += __shfl_xor(s2, off);
    }
    if (lane == 0) {
        const float mu = s * (1.0f / 256.0f);
        const float var = s2 * (1.0f / 256.0f) - mu * mu;
        st[(size_t)row * 2 + 0] = mu;
        st[(size_t)row * 2 + 1] = rsqrtf(var + EPSF);
    }
}

// ===========================================================================
// GEMM kernels: block 256 (4 waves). Block owns a 64-col weight slice staged
// ONCE into LDS (batched loads), then loops token tiles with register-
// prefetched double-buffered A tiles. Wave w owns cols [16w,16w+16).
// ===========================================================================

// ---- proj_in: tok0 f32 + vbuf bf16. grid 256 = (4 chunks x 64 strips x 4 tiles)
__global__ __launch_bounds__(256) void k_proj_in(
    const ushort* __restrict__ tin, const ushort* __restrict__ wb,
    const float* __restrict__ bias, float* __restrict__ tok0,
    ushort* __restrict__ vbuf)
{
    __shared__ ushort Wlds[64 * 264];
    __shared__ ushort At[2][16 * 264];
    const int chunk = blockIdx.x & 3, strip = blockIdx.x >> 2;
    const int tid = threadIdx.x, wv = tid >> 6, lane = tid & 63;
    const int c = lane & 15, g = lane >> 4;

    {   // stage weights: 64 rows x 256, 8 ushort8/thread
        const int wr = tid >> 2, wc = (tid & 3) * 64;
        const ushort* wp = wb + (size_t)(chunk * 64 + wr) * 256 + wc;
#pragma unroll
        for (int i = 0; i < 8; ++i)
            *(ushort8*)&Wlds[wr * 264 + wc + i * 8] = *(const ushort8*)(wp + i * 8);
    }
    const int r = tid >> 4, c0a = (tid & 15) * 16;
    const int t0 = strip * 64;
    ushort8 pre0 = *(const ushort8*)(tin + (size_t)(t0 + r) * 256 + c0a);
    ushort8 pre1 = *(const ushort8*)(tin + (size_t)(t0 + r) * 256 + c0a + 8);

    const int col = chunk * 64 + wv * 16 + c;
    const float bb = bias[col];
    int p = 0;
#pragma unroll
    for (int tile = 0; tile < 4; ++tile) {
        *(ushort8*)&At[p][r * 264 + c0a] = pre0;
        *(ushort8*)&At[p][r * 264 + c0a + 8] = pre1;
        __syncthreads();
        if (tile < 3) {
            pre0 = *(const ushort8*)(tin + (size_t)(t0 + 16 * (tile + 1) + r) * 256 + c0a);
            pre1 = *(const ushort8*)(tin + (size_t)(t0 + 16 * (tile + 1) + r) * 256 + c0a + 8);
        }
        f32x4 acc = {};
#pragma unroll
        for (int kc = 0; kc < 8; ++kc) {
            const bf16x8 af = *(const bf16x8*)&At[p][c * 264 + kc * 32 + g * 8];
            const bf16x8 wf = *(const bf16x8*)&Wlds[(wv * 16 + c) * 264 + kc * 32 + g * 8];
            acc = MFMA16(af, wf, acc);
        }
        const int tt = t0 + tile * 16;
#pragma unroll
        for (int rr = 0; rr < 4; ++rr) {
            const float v = acc[rr] + bb;
            const size_t idx = (size_t)(tt + 4 * g + rr) * 256 + col;
            tok0[idx] = v;
            vbuf[idx] = (ushort)f2bf(v);
        }
        p ^= 1;
    }
}

// ---- qkv: LN1-folded. grid 384 = (12 chunks x 32 strips x 8 tiles)
__global__ __launch_bounds__(256) void k_qkv(
    const ushort* __restrict__ vbuf, const ushort* __restrict__ wb,
    const float* __restrict__ lnst, const float* __restrict__ u_all,
    const float* __restrict__ d_all, ushort* __restrict__ qkvb)
{
    __shared__ ushort Wlds[64 * 264];
    __shared__ ushort At[2][16 * 264];
    const int chunk = blockIdx.x % 12, strip = blockIdx.x / 12;
    const int tid = threadIdx.x, wv = tid >> 6, lane = tid & 63;
    const int c = lane & 15, g = lane >> 4;

    {
        const int wr = tid >> 2, wc = (tid & 3) * 64;
        const ushort* wp = wb + (size_t)(chunk * 64 + wr) * 256 + wc;
#pragma unroll
        for (int i = 0; i < 8; ++i)
            *(ushort8*)&Wlds[wr * 264 + wc + i * 8] = *(const ushort8*)(wp + i * 8);
    }
    const int r = tid >> 4, c0a = (tid & 15) * 16;
    const int t0 = strip * 128;
    ushort8 pre0 = *(const ushort8*)(vbuf + (size_t)(t0 + r) * 256 + c0a);
    ushort8 pre1 = *(const ushort8*)(vbuf + (size_t)(t0 + r) * 256 + c0a + 8);

    const int col = chunk * 64 + wv * 16 + c;
    const float u = u_all[col], d = d_all[col];
    int p = 0;
#pragma unroll 1
    for (int tile = 0; tile < 8; ++tile) {
        *(ushort8*)&At[p][r * 264 + c0a] = pre0;
        *(ushort8*)&At[p][r * 264 + c0a + 8] = pre1;
        __syncthreads();
        if (tile < 7) {
            pre0 = *(const ushort8*)(vbuf + (size_t)(t0 + 16 * (tile + 1) + r) * 256 + c0a);
            pre1 = *(const ushort8*)(vbuf + (size_t)(t0 + 16 * (tile + 1) + r) * 256 + c0a + 8);
        }
        f32x4 acc = {};
#pragma unroll
        for (int kc = 0; kc < 8; ++kc) {
            const bf16x8 af = *(const bf16x8*)&At[p][c * 264 + kc * 32 + g * 8];
            const bf16x8 wf = *(const bf16x8*)&Wlds[(wv * 16 + c) * 264 + kc * 32 + g * 8];
            acc = MFMA16(af, wf, acc);
        }
        const int tt = t0 + tile * 16;
#pragma unroll
        for (int rr = 0; rr < 4; ++rr) {
            const int row = tt + 4 * g + rr;
            const float mu = lnst[(size_t)row * 2 + 0];
            const float rs = lnst[(size_t)row * 2 + 1];
            qkvb[(size_t)row * 768 + col] = (ushort)f2bf(rs * (acc[rr] - mu * u) + d);
        }
        p ^= 1;
    }
}

// ---- attn-proj: combine O partials (staging) + residuals epilogue.
// grid 256 = (4 chunks x 64 strips x 4 tiles). Writes tok1 f32 + v2 bf16.
__global__ __launch_bounds__(256) void k_attnproj(
    const ushort* __restrict__ opart, const float* __restrict__ lpart,
    const ushort* __restrict__ wb, const float* __restrict__ bias,
    const float* __restrict__ tok0, const float* __restrict__ lnst,
    const float* __restrict__ ln1_g, const float* __restrict__ ln1_b,
    float* __restrict__ tok1, ushort* __restrict__ v2buf)
{
    __shared__ ushort Wlds[64 * 264];
    __shared__ ushort At[2][16 * 264];
    const int chunk = blockIdx.x & 3, strip = blockIdx.x >> 2;
    const int tid = threadIdx.x, wv = tid >> 6, lane = tid & 63;
    const int c = lane & 15, g = lane >> 4;

    {
        const int wr = tid >> 2, wc = (tid & 3) * 64;
        const ushort* wp = wb + (size_t)(chunk * 64 + wr) * 256 + wc;
#pragma unroll
        for (int i = 0; i < 8; ++i)
            *(ushort8*)&Wlds[wr * 264 + wc + i * 8] = *(const ushort8*)(wp + i * 8);
    }
    const int r = tid >> 4, c0a = (tid & 15) * 16;
    const int hh = c0a >> 5;
    const int t0 = strip * 64;

    ushort4 pa[4][4];
    float linv;
    {
        const float* lp = lpart + (size_t)(t0 + r) * 32;
        linv = 1.0f / (lp[hh] + lp[8 + hh] + lp[16 + hh] + lp[24 + hh]);
        const size_t base = (size_t)(t0 + r) * 256 + c0a;
#pragma unroll
        for (int cc = 0; cc < 4; ++cc)
#pragma unroll
            for (int q = 0; q < 4; ++q)
                pa[cc][q] = *(const ushort4*)(opart + ((size_t)q << 20) + base + cc * 4);
    }

    const int col = chunk * 64 + wv * 16 + c;
    const float bb = bias[col];
    const float g1 = ln1_g[col], b1 = ln1_b[col];
    int p = 0;
#pragma unroll
    for (int tile = 0; tile < 4; ++tile) {
#pragma unroll
        for (int cc = 0; cc < 4; ++cc) {
            unsigned w[2];
            w[0] = pk_bf16((bf2f(pa[cc][0].x) + bf2f(pa[cc][1].x) + bf2f(pa[cc][2].x) + bf2f(pa[cc][3].x)) * linv,
                           (bf2f(pa[cc][0].y) + bf2f(pa[cc][1].y) + bf2f(pa[cc][2].y) + bf2f(pa[cc][3].y)) * linv);
            w[1] = pk_bf16((bf2f(pa[cc][0].z) + bf2f(pa[cc][1].z) + bf2f(pa[cc][2].z) + bf2f(pa[cc][3].z)) * linv,
                           (bf2f(pa[cc][0].w) + bf2f(pa[cc][1].w) + bf2f(pa[cc][2].w) + bf2f(pa[cc][3].w)) * linv);
            *(ushort4*)&At[p][r * 264 + c0a + cc * 4] = *(ushort4*)w;
        }
        __syncthreads();
        if (tile < 3) {
            const int tn = t0 + 16 * (tile + 1);
            const float* lp = lpart + (size_t)(tn + r) * 32;
            linv = 1.0f / (lp[hh] + lp[8 + hh] + lp[16 + hh] + lp[24 + hh]);
            const size_t base = (size_t)(tn + r) * 256 + c0a;
#pragma unroll
            for (int cc = 0; cc < 4; ++cc)
#pragma unroll
                for (int q = 0; q < 4; ++q)
                    pa[cc][q] = *(const ushort4*)(opart + ((size_t)q << 20) + base + cc * 4);
        }
        f32x4 acc = {};
#pragma unroll
        for (int kc = 0; kc < 8; ++kc) {
            const bf16x8 af = *(const bf16x8*)&At[p][c * 264 + kc * 32 + g * 8];
            const bf16x8 wf = *(const bf16x8*)&Wlds[(wv * 16 + c) * 264 + kc * 32 + g * 8];
            acc = MFMA16(af, wf, acc);
        }
        const int tt = t0 + tile * 16;
#pragma unroll
        for (int rr = 0; rr < 4; ++rr) {
            const int row = tt + 4 * g + rr;
            const size_t idx = (size_t)row * 256 + col;
            const float t0v = tok0[idx];
            const float mu = lnst[(size_t)row * 2 + 0];
            const float rs = lnst[(size_t)row * 2 + 1];
            const float y = (t0v - mu) * rs * g1 + b1;
            const float v = acc[rr] + bb + y + t0v;
            tok1[idx] = v;
            v2buf[idx] = (ushort)f2bf(v);
        }
        p ^= 1;
    }
}

// ---- ff1: LN2-folded + gelu. grid 512 = (16 chunks x 32 strips x 8 tiles)
__global__ __launch_bounds__(256) void k_ff1(
    const ushort* __restrict__ v2buf, const ushort* __restrict__ wb,
    const float* __restrict__ lnst, const float* __restrict__ u_all,
    const float* __restrict__ d_all, ushort* __restrict__ zbuf)
{
    __shared__ ushort Wlds[64 * 264];
    __shared__ ushort At[2][16 * 264];
    const int chunk = blockIdx.x & 15, strip = blockIdx.x >> 4;
    const int tid = threadIdx.x, wv = tid >> 6, lane = tid & 63;
    const int c = lane & 15, g = lane >> 4;

    {
        const int wr = tid >> 2, wc = (tid & 3) * 64;
        const ushort* wp = wb + (size_t)(chunk * 64 + wr) * 256 + wc;
#pragma unroll
        for (int i = 0; i < 8; ++i)
            *(ushort8*)&Wlds[wr * 264 + wc + i * 8] = *(const ushort8*)(wp + i * 8);
    }
    const int r = tid >> 4, c0a = (tid & 15) * 16;
    const int t0 = strip * 128;
    ushort8 pre0 = *(const ushort8*)(v2buf + (size_t)(t0 + r) * 256 + c0a);
    ushort8 pre1 = *(const ushort8*)(v2buf + (size_t)(t0 + r) * 256 + c0a + 8);

    const int col = chunk * 64 + wv * 16 + c;
    const float u = u_all[768 + col], d = d_all[768 + col];
    int p = 0;
#pragma unroll 1
    for (int tile = 0; tile < 8; ++tile) {
        *(ushort8*)&At[p][r * 264 + c0a] = pre0;
        *(ushort8*)&At[p][r * 264 + c0a + 8] = pre1;
        __syncthreads();
        if (tile < 7) {
            pre0 = *(const ushort8*)(v2buf + (size_t)(t0 + 16 * (tile + 1) + r) * 256 + c0a);
            pre1 = *(const ushort8*)(v2buf + (size_t)(t0 + 16 * (tile + 1) + r) * 256 + c0a + 8);
        }
        f32x4 acc = {};
#pragma unroll
        for (int kc = 0; kc < 8; ++kc) {
            const bf16x8 af = *(const bf16x8*)&At[p][c * 264 + kc * 32 + g * 8];
            const bf16x8 wf = *(const bf16x8*)&Wlds[(wv * 16 + c) * 264 + kc * 32 + g * 8];
            acc = MFMA16(af, wf, acc);
        }
        const int tt = t0 + tile * 16;
#pragma unroll
        for (int rr = 0; rr < 4; ++rr) {
            const int row = tt + 4 * g + rr;
            const float mu = lnst[(size_t)row * 2 + 0];
            const float rs = lnst[(size_t)row * 2 + 1];
            float v = rs * (acc[rr] - mu * u) + d;
            v = 0.5f * v * (1.0f + erff(v * 0.70710678118654752f));
            zbuf[(size_t)row * 1024 + col] = (ushort)f2bf(v);
        }
        p ^= 1;
    }
}

// ---- ff2: K=1024, 32-col chunks; 2 col-waves x 2 token-subtiles.
// grid 256 = (8 chunks x 32 strips x 4 iters of 32 tokens).
__global__ __launch_bounds__(256) void k_ff2(
    const ushort* __restrict__ zbuf, const ushort* __restrict__ wb,
    const float* __restrict__ bias, const float* __restrict__ tok1,
    ushort* __restrict__ tok2)
{
    __shared__ ushort Wlds[32 * 1032];
    __shared__ ushort At[32 * 1032];
    const int chunk = blockIdx.x & 7, strip = blockIdx.x >> 3;
    const int tid = threadIdx.x, wv = tid >> 6, lane = tid & 63;
    const int c = lane & 15, g = lane >> 4;

    {   // stage weights: 32 rows x 1024, 16 ushort8/thread
        const int wr = tid >> 3, wc = (tid & 7) * 128;
        const ushort* wp = wb + (size_t)(chunk * 32 + wr) * 1024 + wc;
#pragma unroll
        for (int i = 0; i < 16; ++i)
            *(ushort8*)&Wlds[wr * 1032 + wc + i * 8] = *(const ushort8*)(wp + i * 8);
    }
    const int r = tid >> 3, c0a = (tid & 7) * 128;
    const int t0 = strip * 128;
    ushort8 preZ[16];
#pragma unroll
    for (int i = 0; i < 16; ++i)
        preZ[i] = *(const ushort8*)(zbuf + (size_t)(t0 + r) * 1024 + c0a + i * 8);

    const int sub = wv >> 1, cw = (wv & 1) * 16;
    const int col = chunk * 32 + cw + c;
    const float bb = bias[col];
#pragma unroll 1
    for (int it = 0; it < 4; ++it) {
#pragma unroll
        for (int i = 0; i < 16; ++i)
            *(ushort8*)&At[r * 1032 + c0a + i * 8] = preZ[i];
        __syncthreads();
        if (it < 3) {
            const int tn = t0 + 32 * (it + 1);
#pragma unroll
            for (int i = 0; i < 16; ++i)
                preZ[i] = *(const ushort8*)(zbuf + (size_t)(tn + r) * 1024 + c0a + i * 8);
        }
        f32x4 acc = {};
#pragma unroll
        for (int kc = 0; kc < 32; ++kc) {
            const bf16x8 af = *(const bf16x8*)&At[(sub * 16 + c) * 1032 + kc * 32 + g * 8];
            const bf16x8 wf = *(const bf16x8*)&Wlds[(cw + c) * 1032 + kc * 32 + g * 8];
            acc = MFMA16(af, wf, acc);
        }
        const int tt = t0 + it * 32 + sub * 16;
#pragma unroll
        for (int rr = 0; rr < 4; ++rr) {
            const size_t idx = (size_t)(tt + 4 * g + rr) * 256 + col;
            tok2[idx] = (ushort)f2bf(acc[rr] + bb + tok1[idx]);
        }
        __syncthreads();   // single-buffered A: drain reads before next store
    }
}

// ---- proj_out: out[och][t] = W@tok2^T + b + x. grid 256 = (4 chunks x 64 strips)
__global__ __launch_bounds__(256) void k_pout(
    const ushort* __restrict__ tok2, const ushort* __restrict__ wb,
    const float* __restrict__ b_out, const float* __restrict__ x,
    float* __restrict__ out)
{
    __shared__ ushort Wlds[64 * 264];
    __shared__ ushort At[2][16 * 264];
    const int chunk = blockIdx.x & 3, strip = blockIdx.x >> 2;
    const int tid = threadIdx.x, wv = tid >> 6, lane = tid & 63;
    const int c = lane & 15, g = lane >> 4;

    {
        const int wr = tid >> 2, wc = (tid & 3) * 64;
        const ushort* wp = wb + (size_t)(chunk * 64 + wr) * 256 + wc;
#pragma unroll
        for (int i = 0; i < 8; ++i)
            *(ushort8*)&Wlds[wr * 264 + wc + i * 8] = *(const ushort8*)(wp + i * 8);
    }
    const int r = tid >> 4, c0a = (tid & 15) * 16;
    const int t0 = strip * 64;
    ushort8 pre0 = *(const ushort8*)(tok2 + (size_t)(t0 + r) * 256 + c0a);
    ushort8 pre1 = *(const ushort8*)(tok2 + (size_t)(t0 + r) * 256 + c0a + 8);

    int p = 0;
#pragma unroll
    for (int tile = 0; tile < 4; ++tile) {
        *(ushort8*)&At[p][r * 264 + c0a] = pre0;
        *(ushort8*)&At[p][r * 264 + c0a + 8] = pre1;
        __syncthreads();
        if (tile < 3) {
            pre0 = *(const ushort8*)(tok2 + (size_t)(t0 + 16 * (tile + 1) + r) * 256 + c0a);
            pre1 = *(const ushort8*)(tok2 + (size_t)(t0 + 16 * (tile + 1) + r) * 256 + c0a + 8);
        }
        f32x4 acc = {};
#pragma unroll
        for (int kc = 0; kc < 8; ++kc) {
            const bf16x8 wf = *(const bf16x8*)&Wlds[(wv * 16 + c) * 264 + kc * 32 + g * 8];
            const bf16x8 bf = *(const bf16x8*)&At[p][c * 264 + kc * 32 + g * 8];
            acc = MFMA16(wf, bf, acc);
        }
        const int tt = t0 + tile * 16;
#pragma unroll
        for (int rr = 0; rr < 4; ++rr) {
            const int och = chunk * 64 + wv * 16 + 4 * g + rr;
            const size_t idx = (size_t)och * T_TOK + tt + c;
            out[idx] = acc[rr] + b_out[och] + x[idx];
        }
        p ^= 1;
    }
}

// ---------------------------------------------------------------------------
// Flash attention (unchanged, proven): no-max exp2 softmax, split-K x4.
// ---------------------------------------------------------------------------
#define KS   40
#define VTS  72
#define PS_W 34

__global__ __launch_bounds__(256) void attn_mfma(
    const ushort* __restrict__ qkv, ushort* __restrict__ opart,
    float* __restrict__ lpart)
{
    const int h    = blockIdx.y;
    const int q0   = blockIdx.x << 6;
    const int half = blockIdx.z;
    const int tid  = threadIdx.x;
    const int wv   = tid >> 6, lane = tid & 63;
    const int c    = lane & 15, g = lane >> 4;

    __shared__ ushort Ks[2][64 * KS];
    __shared__ ushort Vt[2][32 * VTS];
    __shared__ float  Ps[4][16 * PS_W];

    const bf16x8 qf = *(const bf16x8*)(qkv + (size_t)(q0 + wv * 16 + c) * 768 + h * 32 + g * 8);

    bf16x8 ones;
#pragma unroll
    for (int i = 0; i < 8; ++i) ones[i] = (short)0x3F80;

    f32x4 oacc0 = {0.f, 0.f, 0.f, 0.f};
    f32x4 oacc1 = {0.f, 0.f, 0.f, 0.f};
    f32x4 oaccl = {0.f, 0.f, 0.f, 0.f};

    const int kr = tid >> 2, kc = (tid & 3) * 8;
    const int vp = tid & 31, vd = (tid >> 5) * 4;
    const ushort* kbase = qkv + 256 + h * 32;
    const ushort* vbase = qkv + 512 + h * 32;

    const int kt0 = half * 16, kt1 = kt0 + 16;
    ushort8 kpre  = *(const ushort8*)(kbase + ((size_t)kt0 * 64 + kr) * 768 + kc);
    ushort4 vpre0 = *(const ushort4*)(vbase + ((size_t)kt0 * 64 + 2 * vp) * 768 + vd);
    ushort4 vpre1 = *(const ushort4*)(vbase + ((size_t)kt0 * 64 + 2 * vp + 1) * 768 + vd);

    int p = 0;
    for (int kt = kt0; kt < kt1; ++kt) {
        *(ushort8*)&Ks[p][kr * KS + kc] = kpre;
        {
            unsigned* vtp = (unsigned*)&Vt[p][0];
            vtp[(vd + 0) * (VTS / 2) + vp] = (unsigned)vpre0.x | ((unsigned)vpre1.x << 16);
            vtp[(vd + 1) * (VTS / 2) + vp] = (unsigned)vpre0.y | ((unsigned)vpre1.y << 16);
            vtp[(vd + 2) * (VTS / 2) + vp] = (unsigned)vpre0.z | ((unsigned)vpre1.z << 16);
            vtp[(vd + 3) * (VTS / 2) + vp] = (unsigned)vpre0.w | ((unsigned)vpre1.w << 16);
        }
        __syncthreads();
        if (kt + 1 < kt1) {
            const size_t t0 = (size_t)(kt + 1) * 64;
            kpre  = *(const ushort8*)(kbase + (t0 + kr) * 768 + kc);
            vpre0 = *(const ushort4*)(vbase + (t0 + 2 * vp) * 768 + vd);
            vpre1 = *(const ushort4*)(vbase + (t0 + 2 * vp + 1) * 768 + vd);
        }

        const ushort* ks = &Ks[p][0];
        const ushort* vt = &Vt[p][0];
        const f32x4 zz = {0.f, 0.f, 0.f, 0.f};
        const bf16x8 k0 = *(const bf16x8*)&ks[(0 * 16 + c) * KS + g * 8];
        const bf16x8 k1 = *(const bf16x8*)&ks[(1 * 16 + c) * KS + g * 8];
        const bf16x8 k2 = *(const bf16x8*)&ks[(2 * 16 + c) * KS + g * 8];
        const bf16x8 k3 = *(const bf16x8*)&ks[(3 * 16 + c) * KS + g * 8];
        const f32x4 s0 = MFMA16(k0, qf, zz);
        const f32x4 s1 = MFMA16(k1, qf, zz);
        const f32x4 s2 = MFMA16(k2, qf, zz);
        const f32x4 s3 = MFMA16(k3, qf, zz);

        float* prow = &Ps[wv][c * PS_W];
        {
            const float e00 = __builtin_amdgcn_exp2f(s0[0]), e01 = __builtin_amdgcn_exp2f(s0[1]);
            const float e02 = __builtin_amdgcn_exp2f(s0[2]), e03 = __builtin_amdgcn_exp2f(s0[3]);
            const float e10 = __builtin_amdgcn_exp2f(s1[0]), e11 = __builtin_amdgcn_exp2f(s1[1]);
            const float e12 = __builtin_amdgcn_exp2f(s1[2]), e13 = __builtin_amdgcn_exp2f(s1[3]);
            const float e20 = __builtin_amdgcn_exp2f(s2[0]), e21 = __builtin_amdgcn_exp2f(s2[1]);
            const float e22 = __builtin_amdgcn_exp2f(s2[2]), e23 = __builtin_amdgcn_exp2f(s2[3]);
            const float e30 = __builtin_amdgcn_exp2f(s3[0]), e31 = __builtin_amdgcn_exp2f(s3[1]);
            const float e32 = __builtin_amdgcn_exp2f(s3[2]), e33 = __builtin_amdgcn_exp2f(s3[3]);
            prow[0 * 8 + 2 * g + 0] = __builtin_bit_cast(float, pk_bf16(e00, e01));
            prow[0 * 8 + 2 * g + 1] = __builtin_bit_cast(float, pk_bf16(e02, e03));
            prow[1 * 8 + 2 * g + 0] = __builtin_bit_cast(float, pk_bf16(e10, e11));
            prow[1 * 8 + 2 * g + 1] = __builtin_bit_cast(float, pk_bf16(e12, e13));
            prow[2 * 8 + 2 * g + 0] = __builtin_bit_cast(float, pk_bf16(e20, e21));
            prow[2 * 8 + 2 * g + 1] = __builtin_bit_cast(float, pk_bf16(e22, e23));
            prow[3 * 8 + 2 * g + 0] = __builtin_bit_cast(float, pk_bf16(e30, e31));
            prow[3 * 8 + 2 * g + 1] = __builtin_bit_cast(float, pk_bf16(e32, e33));
        }
#pragma unroll
        for (int ch = 0; ch < 2; ++ch) {
            const float2 pA = *(const float2*)&prow[ch * 16 + 4 * g];
            const float2 pB = *(const float2*)&prow[ch * 16 + 4 * g + 2];
            unsigned pw[4];
            pw[0] = __builtin_bit_cast(unsigned, pA.x);
            pw[1] = __builtin_bit_cast(unsigned, pA.y);
            pw[2] = __builtin_bit_cast(unsigned, pB.x);
            pw[3] = __builtin_bit_cast(unsigned, pB.y);
            const bf16x8 pf = *(const bf16x8*)pw;
            const bf16x8 v0 = *(const bf16x8*)&vt[(c)      * VTS + ch * 32 + g * 8];
            const bf16x8 v1 = *(const bf16x8*)&vt[(16 + c) * VTS + ch * 32 + g * 8];
            oacc0 = MFMA16(pf, v0, oacc0);
            oacc1 = MFMA16(pf, v1, oacc1);
            oaccl = MFMA16(pf, ones, oaccl);
        }
        p ^= 1;
        __syncthreads();
    }

    {
        ushort* op = opart + (size_t)half * (1u << 20) + (size_t)(q0 + wv * 16) * 256 + h * 32;
#pragma unroll
        for (int rr = 0; rr < 4; ++rr) {
            op[(4 * g + rr) * 256 + c]      = (ushort)f2bf(oacc0[rr]);
            op[(4 * g + rr) * 256 + 16 + c] = (ushort)f2bf(oacc1[rr]);
        }
        if (c == 0) {
#pragma unroll
            for (int rr = 0; rr < 4; ++rr)
                lpart[(size_t)(q0 + wv * 16 + 4 * g + rr) * 32 + half * 8 + h] = oaccl[rr];
        }
    }
}

// ---------------------------------------------------------------------------
extern "C" void kernel_launch(void* const* d_in, const int* in_sizes, int n_in,
                              void* d_out, int out_size, void* d_ws, size_t ws_size,
                              hipStream_t stream)
{
    const float* x     = (const float*)d_in[0];
    const float* bn_g  = (const float*)d_in[1];
    const float* bn_b  = (const float*)d_in[2];
    const float* bn_m  = (const float*)d_in[3];
    const float* bn_v  = (const float*)d_in[4];
    const float* w_in  = (const float*)d_in[5];
    const float* b_in  = (const float*)d_in[6];
    const float* ln1_g = (const float*)d_in[7];
    const float* ln1_b = (const float*)d_in[8];
    const float* w_qkv = (const float*)d_in[9];
    const float* b_qkv = (const float*)d_in[10];
    const float* w_ap  = (const float*)d_in[11];
    const float* b_ap  = (const float*)d_in[12];
    const float* ln2_g = (const float*)d_in[13];
    const float* ln2_b = (const float*)d_in[14];
    const float* w_ff1 = (const float*)d_in[15];
    const float* b_ff1 = (const float*)d_in[16];
    const float* w_ff2 = (const float*)d_in[17];
    const float* b_ff2 = (const float*)d_in[18];
    const float* w_out = (const float*)d_in[19];
    const float* b_out = (const float*)d_in[20];
    float* out = (float*)d_out;
    float* ws  = (float*)d_ws;

    const size_t MF = 1u << 20;   // 1M f32 = 4 MB
    float*  tok0   = ws;                                   // [0,1M)
    float*  tok1   = ws + MF;                              // [1M,2M)
    float*  lnst1  = ws + 2 * MF;                          // 8K f32
    float*  lnst2  = ws + 2 * MF + 8192;                   // 8K f32
    ushort* tok2   = (ushort*)(ws + 2 * MF + MF / 4);      // [2.25M,2.5M) 2 MB
    ushort* vbuf   = (ushort*)(ws + 2 * MF + MF / 2);      // [2.5M,3M) 2 MB
    ushort* qkv_bf = (ushort*)(ws + 3 * MF);               // [3M,4.5M) 6 MB
    ushort* tin_bf = (ushort*)(ws + 4 * MF + MF / 2);      // [4.5M,5M) 2 MB
    ushort* opart  = tin_bf;                               // alias: 4x2MB = [4.5M,6.5M)
    ushort* v2buf  = (ushort*)(ws + 6 * MF + MF / 2);      // [6.5M,7M) 2 MB
    ushort* zbuf   = (ushort*)(ws + 7 * MF);               // [7M,9M) 8 MB
    float*  lpart  = ws + 9 * MF;                          // 128K f32
    ushort* wbuf   = (ushort*)(ws + 9 * MF + 131072);      // weight arena ~1.85 MB
    const ushort* wb_in  = wbuf;
    const ushort* wb_qkv = wbuf + 65536;
    const ushort* wb_ap  = wbuf + 262144;
    const ushort* wb_ff1 = wbuf + 327680;
    const ushort* wb_ff2 = wbuf + 589824;
    const ushort* wb_out = wbuf + 851968;
    float* u_all = (float*)(wbuf + 917504);
    float* d_all = u_all + 1792;

    prep_kernel<<<2368, 256, 0, stream>>>(
        w_in, w_qkv, w_ap, w_ff1, w_ff2, w_out,
        b_qkv, b_ff1, ln1_g, ln1_b, ln2_g, ln2_b,
        wbuf, u_all, d_all,
        x, bn_g, bn_b, bn_m, bn_v, tin_bf);
    k_proj_in<<<256, 256, 0, stream>>>(tin_bf, wb_in, b_in, tok0, vbuf);
    k_lnstats<<<1024, 256, 0, stream>>>(tok0, lnst1);
    k_qkv<<<384, 256, 0, stream>>>(vbuf, wb_qkv, lnst1, u_all, d_all, qkv_bf);
    attn_mfma<<<dim3(64, 8, 4), 256, 0, stream>>>(qkv_bf, opart, lpart);
    k_attnproj<<<256, 256, 0, stream>>>(opart, lpart, wb_ap, b_ap, tok0, lnst1,
                                        ln1_g, ln1_b, tok1, v2buf);
    k_lnstats<<<1024, 256, 0, stream>>>(tok1, lnst2);
    k_ff1<<<512, 256, 0, stream>>>(v2buf, wb_ff1, lnst2, u_all, d_all, zbuf);
    k_ff2<<<256, 256, 0, stream>>>(zbuf, wb_ff2, b_ff2, tok1, tok2);
    k_pout<<<256, 256, 0, stream>>>(tok2, wb_out, b_out, x, out);
}

// Round 11
// 210.604 us; speedup vs baseline: 1.1381x; 1.0213x over previous
//
#include <hip/hip_runtime.h>
#include <math.h>

#define T_TOK 4096
#define C_DIM 256
#define EPSF  1e-5f
// hd^-0.5 * log2(e): folded into q-rows of the qkv weights -> scores in log2 domain
#define SC_QL (0.17677669529663687f * 1.4426950408889634f)

typedef short  bf16x8  __attribute__((ext_vector_type(8)));
typedef float  f32x4   __attribute__((ext_vector_type(4)));
typedef ushort ushort8 __attribute__((ext_vector_type(8)));

__device__ __forceinline__ short f2bf(float f) {
    unsigned u = __builtin_bit_cast(unsigned, f);
    unsigned r = (u + 0x7FFFu + ((u >> 16) & 1u)) >> 16;
    return (short)r;
}
__device__ __forceinline__ float bf2f(ushort u) {
    return __builtin_bit_cast(float, ((unsigned)u) << 16);
}
__device__ __forceinline__ unsigned pk_bf16(float a, float b) {
    const unsigned ua = __builtin_bit_cast(unsigned, a) + 0x8000u;
    const unsigned ub = __builtin_bit_cast(unsigned, b) + 0x8000u;
    return __builtin_amdgcn_perm(ub, ua, 0x07060302u);
}
#define MFMA16(a, b, c) __builtin_amdgcn_mfma_f32_16x16x32_bf16(a, b, c, 0, 0, 0)

// ---------------------------------------------------------------------------
// prep (proven): weights -> bf16 arena with LN-gamma folding; BN+transpose;
// u/d fold vectors.
// ---------------------------------------------------------------------------
__global__ __launch_bounds__(256) void prep_kernel(
    const float* __restrict__ w_in, const float* __restrict__ w_qkv,
    const float* __restrict__ w_ap, const float* __restrict__ w_ff1,
    const float* __restrict__ w_ff2, const float* __restrict__ w_out,
    const float* __restrict__ b_qkv, const float* __restrict__ b_ff1,
    const float* __restrict__ ln1_g, const float* __restrict__ ln1_b,
    const float* __restrict__ ln2_g, const float* __restrict__ ln2_b,
    ushort* __restrict__ wbuf, float* __restrict__ u_all, float* __restrict__ d_all,
    const float* __restrict__ x, const float* __restrict__ gamma,
    const float* __restrict__ beta, const float* __restrict__ mean,
    const float* __restrict__ var, ushort* __restrict__ tin)
{
    __shared__ float tile[32][33];
    if (blockIdx.x < 896) {
        const int gid = blockIdx.x * 256 + threadIdx.x;
        const int e0 = gid * 4;
        const float* src; int off;
        float4 sc = {1.f, 1.f, 1.f, 1.f};
        if (e0 < 65536)       { src = w_in;  off = e0; }
        else if (e0 < 262144) {
            src = w_qkv; off = e0 - 65536;
            sc = *(const float4*)(ln1_g + (off & 255));
            if (off < 65536) { sc.x *= SC_QL; sc.y *= SC_QL; sc.z *= SC_QL; sc.w *= SC_QL; }
        }
        else if (e0 < 327680) { src = w_ap;  off = e0 - 262144; }
        else if (e0 < 589824) {
            src = w_ff1; off = e0 - 327680;
            sc = *(const float4*)(ln2_g + (off & 255));
        }
        else if (e0 < 851968) { src = w_ff2; off = e0 - 589824; }
        else                  { src = w_out; off = e0 - 851968; }
        const float4 v = *(const float4*)(src + off);
        ushort4 o;
        o.x = (ushort)f2bf(v.x * sc.x); o.y = (ushort)f2bf(v.y * sc.y);
        o.z = (ushort)f2bf(v.z * sc.z); o.w = (ushort)f2bf(v.w * sc.w);
        *(ushort4*)(wbuf + e0) = o;
    } else if (blockIdx.x < 1920) {
        const int bidx = blockIdx.x - 896;
        const int t0 = (bidx & 127) * 32, c0 = (bidx >> 7) * 32;
        const int tx = threadIdx.x & 31, ty = threadIdx.x >> 5;
#pragma unroll
        for (int i = 0; i < 32; i += 8) {
            const int c = c0 + ty + i;
            const float a = rsqrtf(var[c] + EPSF) * gamma[c];
            const float d = beta[c] - mean[c] * a;
            tile[ty + i][tx] = x[c * T_TOK + t0 + tx] * a + d;
        }
        __syncthreads();
#pragma unroll
        for (int i = 0; i < 32; i += 8) {
            const int t = t0 + ty + i;
            tin[t * C_DIM + c0 + tx] = (ushort)f2bf(tile[tx][ty + i]);
        }
    } else {
        const int row = (blockIdx.x - 1920) * 4 + (threadIdx.x >> 6);
        const int lane = threadIdx.x & 63;
        const float* W; const float* gv; const float* bv; float bias; float qs = 1.f;
        if (row < 768) {
            W = w_qkv + (size_t)row * 256; gv = ln1_g; bv = ln1_b; bias = b_qkv[row];
            if (row < 256) qs = SC_QL;
        } else {
            const int r2 = row - 768;
            W = w_ff1 + (size_t)r2 * 256; gv = ln2_g; bv = ln2_b; bias = b_ff1[r2];
        }
        const float4 w4 = *(const float4*)(W + lane * 4);
        const float4 g4 = *(const float4*)(gv + lane * 4);
        const float4 b4 = *(const float4*)(bv + lane * 4);
        float su = w4.x * g4.x + w4.y * g4.y + w4.z * g4.z + w4.w * g4.w;
        float sd = w4.x * b4.x + w4.y * b4.y + w4.z * b4.z + w4.w * b4.w;
#pragma unroll
        for (int off = 32; off > 0; off >>= 1) {
            su += __shfl_xor(su, off);
            sd += __shfl_xor(sd, off);
        }
        if (lane == 0) {
            u_all[row] = qs * su;
            d_all[row] = qs * (sd + bias);
        }
    }
}

// ---------------------------------------------------------------------------
// LN stats: one wave per row of 256 f32 -> (mu, rs).
// ---------------------------------------------------------------------------
__global__ __launch_bounds__(256) void k_lnstats(
    const float* __restrict__ in, float* __restrict__ st)
{
    const int row = blockIdx.x * 4 + (threadIdx.x >> 6);
    const int lane = threadIdx.x & 63;
    const float4 v = *(const float4*)(in + (size_t)row * 256 + lane * 4);
    float s  = v.x + v.y + v.z + v.w;
    float s2 = v.x * v.x + v.y * v.y + v.z * v.z + v.w * v.w;
#pragma unroll
    for (int off = 32; off > 0; off >>= 1) {
        s  += __shfl_xor(s, off);
        s2 += __shfl_xor(s2, off);
    }
    if (lane == 0) {
        const float mu = s * (1.0f / 256.0f);
        const float var = s2 * (1.0f / 256.0f) - mu * mu;
        st[(size_t)row * 2 + 0] = mu;
        st[(size_t)row * 2 + 1] = rsqrtf(var + EPSF);
    }
}

// ===========================================================================
// GEMM kernels: 256-thr blocks, register-resident weights (8x16B independent
// loads/lane at entry), A tiles in small LDS, grids >= 1024 for 4-8 blocks/CU.
// ===========================================================================

// ---- proj_in: 1 tile/block. grid 1024 = 4 chunks x 256 strips.
__global__ __launch_bounds__(256) void k_proj_in(
    const ushort* __restrict__ tin, const ushort* __restrict__ wb,
    const float* __restrict__ bias, float* __restrict__ tok0,
    ushort* __restrict__ vbuf)
{
    __shared__ ushort At[16 * 264];
    const int chunk = blockIdx.x & 3, strip = blockIdx.x >> 2;
    const int tid = threadIdx.x, wv = tid >> 6, lane = tid & 63;
    const int c = lane & 15, g = lane >> 4;
    const int col = chunk * 64 + wv * 16 + c;
    const int t0 = strip * 16;

    bf16x8 w[8];
#pragma unroll
    for (int kc = 0; kc < 8; ++kc)
        w[kc] = *(const bf16x8*)(wb + (size_t)col * 256 + kc * 32 + g * 8);
    {
        const int r = tid >> 4, c0 = (tid & 15) * 16;
        *(ushort8*)&At[r * 264 + c0]     = *(const ushort8*)(tin + (size_t)(t0 + r) * 256 + c0);
        *(ushort8*)&At[r * 264 + c0 + 8] = *(const ushort8*)(tin + (size_t)(t0 + r) * 256 + c0 + 8);
    }
    __syncthreads();
    f32x4 acc = {};
#pragma unroll
    for (int kc = 0; kc < 8; ++kc)
        acc = MFMA16(*(const bf16x8*)&At[c * 264 + kc * 32 + g * 8], w[kc], acc);
    const float bb = bias[col];
#pragma unroll
    for (int rr = 0; rr < 4; ++rr) {
        const float v = acc[rr] + bb;
        const size_t idx = (size_t)(t0 + 4 * g + rr) * 256 + col;
        tok0[idx] = v;
        vbuf[idx] = (ushort)f2bf(v);
    }
}

// ---- qkv: LN1-folded, 2 tiles/block dbuf. grid 1536 = 12 chunks x 128 strips.
__global__ __launch_bounds__(256) void k_qkv(
    const ushort* __restrict__ vbuf, const ushort* __restrict__ wb,
    const float* __restrict__ lnst, const float* __restrict__ u_all,
    const float* __restrict__ d_all, ushort* __restrict__ qkvb)
{
    __shared__ ushort At[2][16 * 264];
    const int chunk = blockIdx.x % 12, strip = blockIdx.x / 12;
    const int tid = threadIdx.x, wv = tid >> 6, lane = tid & 63;
    const int c = lane & 15, g = lane >> 4;
    const int col = chunk * 64 + wv * 16 + c;
    const int t0 = strip * 32;
    const int r = tid >> 4, c0 = (tid & 15) * 16;

    bf16x8 w[8];
#pragma unroll
    for (int kc = 0; kc < 8; ++kc)
        w[kc] = *(const bf16x8*)(wb + (size_t)col * 256 + kc * 32 + g * 8);
    ushort8 pre0 = *(const ushort8*)(vbuf + (size_t)(t0 + r) * 256 + c0);
    ushort8 pre1 = *(const ushort8*)(vbuf + (size_t)(t0 + r) * 256 + c0 + 8);

    const float u = u_all[col], d = d_all[col];
#pragma unroll
    for (int tile = 0; tile < 2; ++tile) {
        *(ushort8*)&At[tile][r * 264 + c0]     = pre0;
        *(ushort8*)&At[tile][r * 264 + c0 + 8] = pre1;
        __syncthreads();
        if (tile == 0) {
            pre0 = *(const ushort8*)(vbuf + (size_t)(t0 + 16 + r) * 256 + c0);
            pre1 = *(const ushort8*)(vbuf + (size_t)(t0 + 16 + r) * 256 + c0 + 8);
        }
        f32x4 acc = {};
#pragma unroll
        for (int kc = 0; kc < 8; ++kc)
            acc = MFMA16(*(const bf16x8*)&At[tile][c * 264 + kc * 32 + g * 8], w[kc], acc);
        const int tt = t0 + tile * 16;
#pragma unroll
        for (int rr = 0; rr < 4; ++rr) {
            const int row = tt + 4 * g + rr;
            const float mu = lnst[(size_t)row * 2 + 0];
            const float rs = lnst[(size_t)row * 2 + 1];
            qkvb[(size_t)row * 768 + col] = (ushort)f2bf(rs * (acc[rr] - mu * u) + d);
        }
    }
}

// ---- attn-proj: combine O partials in staging + residual epilogue.
// 1 tile/block. grid 1024 = 4 chunks x 256 strips.
__global__ __launch_bounds__(256) void k_attnproj(
    const ushort* __restrict__ opart, const float* __restrict__ lpart,
    const ushort* __restrict__ wb, const float* __restrict__ bias,
    const float* __restrict__ tok0, const float* __restrict__ lnst,
    const float* __restrict__ ln1_g, const float* __restrict__ ln1_b,
    float* __restrict__ tok1, ushort* __restrict__ v2buf)
{
    __shared__ ushort At[16 * 264];
    const int chunk = blockIdx.x & 3, strip = blockIdx.x >> 2;
    const int tid = threadIdx.x, wv = tid >> 6, lane = tid & 63;
    const int c = lane & 15, g = lane >> 4;
    const int col = chunk * 64 + wv * 16 + c;
    const int t0 = strip * 16;

    bf16x8 w[8];
#pragma unroll
    for (int kc = 0; kc < 8; ++kc)
        w[kc] = *(const bf16x8*)(wb + (size_t)col * 256 + kc * 32 + g * 8);
    {
        const int r = tid >> 4, c0 = (tid & 15) * 16;
        const int hh = c0 >> 5;
        const float* lp = lpart + (size_t)(t0 + r) * 32;
        const float inv = 1.0f / (lp[hh] + lp[8 + hh] + lp[16 + hh] + lp[24 + hh]);
        const size_t base = (size_t)(t0 + r) * 256 + c0;
#pragma unroll
        for (int cc = 0; cc < 4; ++cc) {
            const ushort4 a0 = *(const ushort4*)(opart + base + cc * 4);
            const ushort4 a1 = *(const ushort4*)(opart + (1u << 20) + base + cc * 4);
            const ushort4 a2 = *(const ushort4*)(opart + (2u << 20) + base + cc * 4);
            const ushort4 a3 = *(const ushort4*)(opart + (3u << 20) + base + cc * 4);
            unsigned wpk[2];
            wpk[0] = pk_bf16((bf2f(a0.x) + bf2f(a1.x) + bf2f(a2.x) + bf2f(a3.x)) * inv,
                             (bf2f(a0.y) + bf2f(a1.y) + bf2f(a2.y) + bf2f(a3.y)) * inv);
            wpk[1] = pk_bf16((bf2f(a0.z) + bf2f(a1.z) + bf2f(a2.z) + bf2f(a3.z)) * inv,
                             (bf2f(a0.w) + bf2f(a1.w) + bf2f(a2.w) + bf2f(a3.w)) * inv);
            *(ushort4*)&At[r * 264 + c0 + cc * 4] = *(ushort4*)wpk;
        }
    }
    __syncthreads();
    f32x4 acc = {};
#pragma unroll
    for (int kc = 0; kc < 8; ++kc)
        acc = MFMA16(*(const bf16x8*)&At[c * 264 + kc * 32 + g * 8], w[kc], acc);
    const float bb = bias[col];
    const float g1 = ln1_g[col], b1 = ln1_b[col];
#pragma unroll
    for (int rr = 0; rr < 4; ++rr) {
        const int row = t0 + 4 * g + rr;
        const size_t idx = (size_t)row * 256 + col;
        const float t0v = tok0[idx];
        const float mu = lnst[(size_t)row * 2 + 0];
        const float rs = lnst[(size_t)row * 2 + 1];
        const float y = (t0v - mu) * rs * g1 + b1;
        const float v = acc[rr] + bb + y + t0v;
        tok1[idx] = v;
        v2buf[idx] = (ushort)f2bf(v);
    }
}

// ---- ff1: LN2-folded + gelu, 2 tiles/block dbuf. grid 2048 = 16 x 128.
__global__ __launch_bounds__(256) void k_ff1(
    const ushort* __restrict__ v2buf, const ushort* __restrict__ wb,
    const float* __restrict__ lnst, const float* __restrict__ u_all,
    const float* __restrict__ d_all, ushort* __restrict__ zbuf)
{
    __shared__ ushort At[2][16 * 264];
    const int chunk = blockIdx.x & 15, strip = blockIdx.x >> 4;
    const int tid = threadIdx.x, wv = tid >> 6, lane = tid & 63;
    const int c = lane & 15, g = lane >> 4;
    const int col = chunk * 64 + wv * 16 + c;
    const int t0 = strip * 32;
    const int r = tid >> 4, c0 = (tid & 15) * 16;

    bf16x8 w[8];
#pragma unroll
    for (int kc = 0; kc < 8; ++kc)
        w[kc] = *(const bf16x8*)(wb + (size_t)col * 256 + kc * 32 + g * 8);
    ushort8 pre0 = *(const ushort8*)(v2buf + (size_t)(t0 + r) * 256 + c0);
    ushort8 pre1 = *(const ushort8*)(v2buf + (size_t)(t0 + r) * 256 + c0 + 8);

    const float u = u_all[768 + col], d = d_all[768 + col];
#pragma unroll
    for (int tile = 0; tile < 2; ++tile) {
        *(ushort8*)&At[tile][r * 264 + c0]     = pre0;
        *(ushort8*)&At[tile][r * 264 + c0 + 8] = pre1;
        __syncthreads();
        if (tile == 0) {
            pre0 = *(const ushort8*)(v2buf + (size_t)(t0 + 16 + r) * 256 + c0);
            pre1 = *(const ushort8*)(v2buf + (size_t)(t0 + 16 + r) * 256 + c0 + 8);
        }
        f32x4 acc = {};
#pragma unroll
        for (int kc = 0; kc < 8; ++kc)
            acc = MFMA16(*(const bf16x8*)&At[tile][c * 264 + kc * 32 + g * 8], w[kc], acc);
        const int tt = t0 + tile * 16;
#pragma unroll
        for (int rr = 0; rr < 4; ++rr) {
            const int row = tt + 4 * g + rr;
            const float mu = lnst[(size_t)row * 2 + 0];
            const float rs = lnst[(size_t)row * 2 + 1];
            float v = rs * (acc[rr] - mu * u) + d;
            v = 0.5f * v * (1.0f + erff(v * 0.70710678118654752f));
            zbuf[(size_t)row * 1024 + col] = (ushort)f2bf(v);
        }
    }
}

// ---- ff2: split-K x2, f32 partials. 2 tiles/block. grid 1024 =
// (4 chunks x 2 halves x 128 strips). 16 reg-weight loads/lane (K=512 half).
__global__ __launch_bounds__(256) void k_ff2(
    const ushort* __restrict__ zbuf, const ushort* __restrict__ wb,
    float* __restrict__ pf2)
{
    __shared__ ushort At[2][16 * 520];
    const int chunk = blockIdx.x & 3, half = (blockIdx.x >> 2) & 1, strip = blockIdx.x >> 3;
    const int tid = threadIdx.x, wv = tid >> 6, lane = tid & 63;
    const int c = lane & 15, g = lane >> 4;
    const int col = chunk * 64 + wv * 16 + c;
    const int t0 = strip * 32;
    const int r = tid >> 4, c0 = (tid & 15) * 32;

    bf16x8 w[16];
#pragma unroll
    for (int kc = 0; kc < 16; ++kc)
        w[kc] = *(const bf16x8*)(wb + (size_t)col * 1024 + half * 512 + kc * 32 + g * 8);
    const ushort* zsrc = zbuf + half * 512;
    ushort8 pre[4];
#pragma unroll
    for (int i = 0; i < 4; ++i)
        pre[i] = *(const ushort8*)(zsrc + (size_t)(t0 + r) * 1024 + c0 + i * 8);

#pragma unroll
    for (int tile = 0; tile < 2; ++tile) {
#pragma unroll
        for (int i = 0; i < 4; ++i)
            *(ushort8*)&At[tile][r * 520 + c0 + i * 8] = pre[i];
        __syncthreads();
        if (tile == 0) {
#pragma unroll
            for (int i = 0; i < 4; ++i)
                pre[i] = *(const ushort8*)(zsrc + (size_t)(t0 + 16 + r) * 1024 + c0 + i * 8);
        }
        f32x4 acc = {};
#pragma unroll
        for (int kc = 0; kc < 16; ++kc)
            acc = MFMA16(*(const bf16x8*)&At[tile][c * 520 + kc * 32 + g * 8], w[kc], acc);
        const int tt = t0 + tile * 16;
        float* op = pf2 + (size_t)half * (1u << 20);
#pragma unroll
        for (int rr = 0; rr < 4; ++rr)
            op[(size_t)(tt + 4 * g + rr) * 256 + col] = acc[rr];
    }
}

// ---- proj_out: combine ff2 partials + b_ff2 + tok1 in staging, then
// out[och][t] = W@tok2^T + b_out + x. 1 tile/block. grid 1024 = 4 x 256.
__global__ __launch_bounds__(256) void k_pout(
    const float* __restrict__ pf2, const float* __restrict__ b_ff2,
    const float* __restrict__ tok1, const ushort* __restrict__ wb,
    const float* __restrict__ b_out, const float* __restrict__ x,
    float* __restrict__ out)
{
    __shared__ ushort At[16 * 264];
    const int chunk = blockIdx.x & 3, strip = blockIdx.x >> 2;
    const int tid = threadIdx.x, wv = tid >> 6, lane = tid & 63;
    const int c = lane & 15, g = lane >> 4;
    const int t0 = strip * 16;

    bf16x8 w[8];
#pragma unroll
    for (int kc = 0; kc < 8; ++kc)
        w[kc] = *(const bf16x8*)(wb +
            (size_t)(chunk * 64 + wv * 16 + c) * 256 + kc * 32 + g * 8);
    {
        const int r = tid >> 4, c0 = (tid & 15) * 16;
        const size_t base = (size_t)(t0 + r) * 256 + c0;
#pragma unroll
        for (int q = 0; q < 4; ++q) {
            const float4 p0 = *(const float4*)(pf2 + base + q * 4);
            const float4 p1 = *(const float4*)(pf2 + (1u << 20) + base + q * 4);
            const float4 tk = *(const float4*)(tok1 + base + q * 4);
            const float4 bf = *(const float4*)(b_ff2 + c0 + q * 4);
            unsigned wpk[2];
            wpk[0] = pk_bf16(p0.x + p1.x + bf.x + tk.x, p0.y + p1.y + bf.y + tk.y);
            wpk[1] = pk_bf16(p0.z + p1.z + bf.z + tk.z, p0.w + p1.w + bf.w + tk.w);
            *(ushort4*)&At[r * 264 + c0 + q * 4] = *(ushort4*)wpk;
        }
    }
    __syncthreads();
    f32x4 acc = {};
#pragma unroll
    for (int kc = 0; kc < 8; ++kc)
        acc = MFMA16(w[kc], *(const bf16x8*)&At[c * 264 + kc * 32 + g * 8], acc);
#pragma unroll
    for (int rr = 0; rr < 4; ++rr) {
        const int och = chunk * 64 + wv * 16 + 4 * g + rr;
        const size_t idx = (size_t)och * T_TOK + t0 + c;
        out[idx] = acc[rr] + b_out[och] + x[idx];
    }
}

// ---------------------------------------------------------------------------
// Flash attention (unchanged, proven): no-max exp2 softmax, split-K x4.
// ---------------------------------------------------------------------------
#define KS   40
#define VTS  72
#define PS_W 34

__global__ __launch_bounds__(256) void attn_mfma(
    const ushort* __restrict__ qkv, ushort* __restrict__ opart,
    float* __restrict__ lpart)
{
    const int h    = blockIdx.y;
    const int q0   = blockIdx.x << 6;
    const int half = blockIdx.z;
    const int tid  = threadIdx.x;
    const int wv   = tid >> 6, lane = tid & 63;
    const int c    = lane & 15, g = lane >> 4;

    __shared__ ushort Ks[2][64 * KS];
    __shared__ ushort Vt[2][32 * VTS];
    __shared__ float  Ps[4][16 * PS_W];

    const bf16x8 qf = *(const bf16x8*)(qkv + (size_t)(q0 + wv * 16 + c) * 768 + h * 32 + g * 8);

    bf16x8 ones;
#pragma unroll
    for (int i = 0; i < 8; ++i) ones[i] = (short)0x3F80;

    f32x4 oacc0 = {0.f, 0.f, 0.f, 0.f};
    f32x4 oacc1 = {0.f, 0.f, 0.f, 0.f};
    f32x4 oaccl = {0.f, 0.f, 0.f, 0.f};

    const int kr = tid >> 2, kc = (tid & 3) * 8;
    const int vp = tid & 31, vd = (tid >> 5) * 4;
    const ushort* kbase = qkv + 256 + h * 32;
    const ushort* vbase = qkv + 512 + h * 32;

    const int kt0 = half * 16, kt1 = kt0 + 16;
    ushort8 kpre  = *(const ushort8*)(kbase + ((size_t)kt0 * 64 + kr) * 768 + kc);
    ushort4 vpre0 = *(const ushort4*)(vbase + ((size_t)kt0 * 64 + 2 * vp) * 768 + vd);
    ushort4 vpre1 = *(const ushort4*)(vbase + ((size_t)kt0 * 64 + 2 * vp + 1) * 768 + vd);

    int p = 0;
    for (int kt = kt0; kt < kt1; ++kt) {
        *(ushort8*)&Ks[p][kr * KS + kc] = kpre;
        {
            unsigned* vtp = (unsigned*)&Vt[p][0];
            vtp[(vd + 0) * (VTS / 2) + vp] = (unsigned)vpre0.x | ((unsigned)vpre1.x << 16);
            vtp[(vd + 1) * (VTS / 2) + vp] = (unsigned)vpre0.y | ((unsigned)vpre1.y << 16);
            vtp[(vd + 2) * (VTS / 2) + vp] = (unsigned)vpre0.z | ((unsigned)vpre1.z << 16);
            vtp[(vd + 3) * (VTS / 2) + vp] = (unsigned)vpre0.w | ((unsigned)vpre1.w << 16);
        }
        __syncthreads();
        if (kt + 1 < kt1) {
            const size_t t0 = (size_t)(kt + 1) * 64;
            kpre  = *(const ushort8*)(kbase + (t0 + kr) * 768 + kc);
            vpre0 = *(const ushort4*)(vbase + (t0 + 2 * vp) * 768 + vd);
            vpre1 = *(const ushort4*)(vbase + (t0 + 2 * vp + 1) * 768 + vd);
        }

        const ushort* ks = &Ks[p][0];
        const ushort* vt = &Vt[p][0];
        const f32x4 zz = {0.f, 0.f, 0.f, 0.f};
        const bf16x8 k0 = *(const bf16x8*)&ks[(0 * 16 + c) * KS + g * 8];
        const bf16x8 k1 = *(const bf16x8*)&ks[(1 * 16 + c) * KS + g * 8];
        const bf16x8 k2 = *(const bf16x8*)&ks[(2 * 16 + c) * KS + g * 8];
        const bf16x8 k3 = *(const bf16x8*)&ks[(3 * 16 + c) * KS + g * 8];
        const f32x4 s0 = MFMA16(k0, qf, zz);
        const f32x4 s1 = MFMA16(k1, qf, zz);
        const f32x4 s2 = MFMA16(k2, qf, zz);
        const f32x4 s3 = MFMA16(k3, qf, zz);

        float* prow = &Ps[wv][c * PS_W];
        {
            const float e00 = __builtin_amdgcn_exp2f(s0[0]), e01 = __builtin_amdgcn_exp2f(s0[1]);
            const float e02 = __builtin_amdgcn_exp2f(s0[2]), e03 = __builtin_amdgcn_exp2f(s0[3]);
            const float e10 = __builtin_amdgcn_exp2f(s1[0]), e11 = __builtin_amdgcn_exp2f(s1[1]);
            const float e12 = __builtin_amdgcn_exp2f(s1[2]), e13 = __builtin_amdgcn_exp2f(s1[3]);
            const float e20 = __builtin_amdgcn_exp2f(s2[0]), e21 = __builtin_amdgcn_exp2f(s2[1]);
            const float e22 = __builtin_amdgcn_exp2f(s2[2]), e23 = __builtin_amdgcn_exp2f(s2[3]);
            const float e30 = __builtin_amdgcn_exp2f(s3[0]), e31 = __builtin_amdgcn_exp2f(s3[1]);
            const float e32 = __builtin_amdgcn_exp2f(s3[2]), e33 = __builtin_amdgcn_exp2f(s3[3]);
            prow[0 * 8 + 2 * g + 0] = __builtin_bit_cast(float, pk_bf16(e00, e01));
            prow[0 * 8 + 2 * g + 1] = __builtin_bit_cast(float, pk_bf16(e02, e03));
            prow[1 * 8 + 2 * g + 0] = __builtin_bit_cast(float, pk_bf16(e10, e11));
            prow[1 * 8 + 2 * g + 1] = __builtin_bit_cast(float, pk_bf16(e12, e13));
            prow[2 * 8 + 2 * g + 0] = __builtin_bit_cast(float, pk_bf16(e20, e21));
            prow[2 * 8 + 2 * g + 1] = __builtin_bit_cast(float, pk_bf16(e22, e23));
            prow[3 * 8 + 2 * g + 0] = __builtin_bit_cast(float, pk_bf16(e30, e31));
            prow[3 * 8 + 2 * g + 1] = __builtin_bit_cast(float, pk_bf16(e32, e33));
        }
#pragma unroll
        for (int ch = 0; ch < 2; ++ch) {
            const float2 pA = *(const float2*)&prow[ch * 16 + 4 * g];
            const float2 pB = *(const float2*)&prow[ch * 16 + 4 * g + 2];
            unsigned pw[4];
            pw[0] = __builtin_bit_cast(unsigned, pA.x);
            pw[1] = __builtin_bit_cast(unsigned, pA.y);
            pw[2] = __builtin_bit_cast(unsigned, pB.x);
            pw[3] = __builtin_bit_cast(unsigned, pB.y);
            const bf16x8 pf = *(const bf16x8*)pw;
            const bf16x8 v0 = *(const bf16x8*)&vt[(c)      * VTS + ch * 32 + g * 8];
            const bf16x8 v1 = *(const bf16x8*)&vt[(16 + c) * VTS + ch * 32 + g * 8];
            oacc0 = MFMA16(pf, v0, oacc0);
            oacc1 = MFMA16(pf, v1, oacc1);
            oaccl = MFMA16(pf, ones, oaccl);
        }
        p ^= 1;
        __syncthreads();
    }

    {
        ushort* op = opart + (size_t)half * (1u << 20) + (size_t)(q0 + wv * 16) * 256 + h * 32;
#pragma unroll
        for (int rr = 0; rr < 4; ++rr) {
            op[(4 * g + rr) * 256 + c]      = (ushort)f2bf(oacc0[rr]);
            op[(4 * g + rr) * 256 + 16 + c] = (ushort)f2bf(oacc1[rr]);
        }
        if (c == 0) {
#pragma unroll
            for (int rr = 0; rr < 4; ++rr)
                lpart[(size_t)(q0 + wv * 16 + 4 * g + rr) * 32 + half * 8 + h] = oaccl[rr];
        }
    }
}

// ---------------------------------------------------------------------------
extern "C" void kernel_launch(void* const* d_in, const int* in_sizes, int n_in,
                              void* d_out, int out_size, void* d_ws, size_t ws_size,
                              hipStream_t stream)
{
    const float* x     = (const float*)d_in[0];
    const float* bn_g  = (const float*)d_in[1];
    const float* bn_b  = (const float*)d_in[2];
    const float* bn_m  = (const float*)d_in[3];
    const float* bn_v  = (const float*)d_in[4];
    const float* w_in  = (const float*)d_in[5];
    const float* b_in  = (const float*)d_in[6];
    const float* ln1_g = (const float*)d_in[7];
    const float* ln1_b = (const float*)d_in[8];
    const float* w_qkv = (const float*)d_in[9];
    const float* b_qkv = (const float*)d_in[10];
    const float* w_ap  = (const float*)d_in[11];
    const float* b_ap  = (const float*)d_in[12];
    const float* ln2_g = (const float*)d_in[13];
    const float* ln2_b = (const float*)d_in[14];
    const float* w_ff1 = (const float*)d_in[15];
    const float* b_ff1 = (const float*)d_in[16];
    const float* w_ff2 = (const float*)d_in[17];
    const float* b_ff2 = (const float*)d_in[18];
    const float* w_out = (const float*)d_in[19];
    const float* b_out = (const float*)d_in[20];
    float* out = (float*)d_out;
    float* ws  = (float*)d_ws;

    const size_t MF = 1u << 20;   // 1M f32 = 4 MB
    float*  tok0   = ws;                                   // [0,1M)
    float*  tok1   = ws + MF;                              // [1M,2M)
    float*  lnst1  = ws + 2 * MF;                          // 8K f32
    float*  lnst2  = ws + 2 * MF + 8192;                   // 8K f32
    ushort* vbuf   = (ushort*)(ws + 2 * MF + MF / 2);      // [2.5M,3M) 2 MB
    ushort* qkv_bf = (ushort*)(ws + 3 * MF);               // [3M,4.5M) 6 MB
    ushort* tin_bf = (ushort*)(ws + 4 * MF + MF / 2);      // [4.5M,5M) 2 MB
    ushort* opart  = tin_bf;                               // alias: 4x2MB = [4.5M,6.5M)
    ushort* v2buf  = (ushort*)(ws + 6 * MF + MF / 2);      // [6.5M,7M) 2 MB
    ushort* zbuf   = (ushort*)(ws + 7 * MF);               // [7M,9M) 8 MB
    float*  lpart  = ws + 9 * MF;                          // 128K f32
    float*  pf2    = ws + 9 * MF + MF / 4;                 // [9.25M,11.25M) 8 MB
    ushort* wbuf   = (ushort*)(ws + 11 * MF + MF / 2);     // weight arena ~1.85 MB
    const ushort* wb_in  = wbuf;
    const ushort* wb_qkv = wbuf + 65536;
    const ushort* wb_ap  = wbuf + 262144;
    const ushort* wb_ff1 = wbuf + 327680;
    const ushort* wb_ff2 = wbuf + 589824;
    const ushort* wb_out = wbuf + 851968;
    float* u_all = (float*)(wbuf + 917504);
    float* d_all = u_all + 1792;

    prep_kernel<<<2368, 256, 0, stream>>>(
        w_in, w_qkv, w_ap, w_ff1, w_ff2, w_out,
        b_qkv, b_ff1, ln1_g, ln1_b, ln2_g, ln2_b,
        wbuf, u_all, d_all,
        x, bn_g, bn_b, bn_m, bn_v, tin_bf);
    k_proj_in<<<1024, 256, 0, stream>>>(tin_bf, wb_in, b_in, tok0, vbuf);
    k_lnstats<<<1024, 256, 0, stream>>>(tok0, lnst1);
    k_qkv<<<1536, 256, 0, stream>>>(vbuf, wb_qkv, lnst1, u_all, d_all, qkv_bf);
    attn_mfma<<<dim3(64, 8, 4), 256, 0, stream>>>(qkv_bf, opart, lpart);
    k_attnproj<<<1024, 256, 0, stream>>>(opart, lpart, wb_ap, b_ap, tok0, lnst1,
                                         ln1_g, ln1_b, tok1, v2buf);
    k_lnstats<<<1024, 256, 0, stream>>>(tok1, lnst2);
    k_ff1<<<2048, 256, 0, stream>>>(v2buf, wb_ff1, lnst2, u_all, d_all, zbuf);
    k_ff2<<<1024, 256, 0, stream>>>(zbuf, wb_ff2, pf2);
    k_pout<<<1024, 256, 0, stream>>>(pf2, b_ff2, tok1, wb_out, b_out, x, out);
}